// Round 5
// baseline (853.955 us; speedup 1.0000x reference)
//
#include <hip/hip_runtime.h>
#include <stdint.h>

#define DEVI static __device__ __forceinline__
typedef unsigned short u16;
typedef __bf16 bhalf8 __attribute__((ext_vector_type(8)));
typedef float f32x4 __attribute__((ext_vector_type(4)));

DEVI u16 f2bf(float f) {
  union { float f; unsigned u; } v; v.f = f;
  unsigned r = v.u + 0x7FFFu + ((v.u >> 16) & 1u);
  return (u16)(r >> 16);
}
DEVI float bf2f(u16 h) {
  union { unsigned u; float f; } v; v.u = ((unsigned)h) << 16;
  return v.f;
}
DEVI f32x4 MFMA(bhalf8 a, bhalf8 b, f32x4 c) {
  return __builtin_amdgcn_mfma_f32_16x16x32_bf16(a, b, c, 0, 0, 0);
}
DEVI bhalf8 LD8(const u16* p) { return *(const bhalf8*)p; }
DEVI f32x4 zero4() { f32x4 z = {0.f, 0.f, 0.f, 0.f}; return z; }

// async global->LDS, 16B per lane, dest = wave-uniform base + lane*16
#define GLDS16(gp, lp) __builtin_amdgcn_global_load_lds( \
    (const __attribute__((address_space(1))) void*)(gp), \
    (__attribute__((address_space(3))) void*)(lp), 16, 0, 0)

// ================= prep / elementwise =================

__global__ __launch_bounds__(64) void nsa_pos_mean(const float* __restrict__ pos, float* __restrict__ pm) {
  int blk = blockIdx.x, l = threadIdx.x;
  const float* p = pos + (size_t)(blk * 64 + l) * 3;
  float a = p[0], b = p[1], c = p[2];
#pragma unroll
  for (int o = 32; o; o >>= 1) { a += __shfl_down(a, o); b += __shfl_down(b, o); c += __shfl_down(c, o); }
  if (l == 0) { pm[blk*3+0] = a * (1.f/64.f); pm[blk*3+1] = b * (1.f/64.f); pm[blk*3+2] = c * (1.f/64.f); }
}

__global__ __launch_bounds__(256) void nsa_hnorm(const float* __restrict__ x, const float* __restrict__ pos,
    const float* __restrict__ pm, const float* __restrict__ pew, const float* __restrict__ peb,
    const float* __restrict__ gamma, u16* __restrict__ hhi, u16* __restrict__ hlo) {
  int n = blockIdx.x, t = threadIdx.x;
  int blk = n >> 6;
  float r0 = pos[(size_t)n*3+0] - pm[blk*3+0];
  float r1 = pos[(size_t)n*3+1] - pm[blk*3+1];
  float r2 = pos[(size_t)n*3+2] - pm[blk*3+2];
  int c0 = t, c1 = t + 256;
  const float* xr = x + (size_t)n * 512;
  float v0 = xr[c0] + r0*pew[c0] + r1*pew[512+c0] + r2*pew[1024+c0] + peb[c0];
  float v1 = xr[c1] + r0*pew[c1] + r1*pew[512+c1] + r2*pew[1024+c1] + peb[c1];
  float ss = v0*v0 + v1*v1;
#pragma unroll
  for (int o = 32; o; o >>= 1) ss += __shfl_down(ss, o);
  __shared__ float red[4];
  if ((t & 63) == 0) red[t >> 6] = ss;
  __syncthreads();
  float rms = 1.0f / sqrtf((red[0]+red[1]+red[2]+red[3]) * (1.0f/512.0f) + 1e-6f);
  float h0 = v0 * rms * gamma[c0], h1 = v1 * rms * gamma[c1];
  u16 a0 = f2bf(h0); hhi[(size_t)n*512+c0] = a0; hlo[(size_t)n*512+c0] = f2bf(h0 - bf2f(a0));
  u16 a1 = f2bf(h1); hhi[(size_t)n*512+c1] = a1; hlo[(size_t)n*512+c1] = f2bf(h1 - bf2f(a1));
}

// WcatT[n][k], n<896: cols of [wq|wk|wv|w_combine|pad]
__global__ __launch_bounds__(256) void nsa_wcatT(const float* __restrict__ wq, const float* __restrict__ wk,
    const float* __restrict__ wv, const float* __restrict__ wc, u16* __restrict__ hi, u16* __restrict__ lo) {
  int idx = blockIdx.x * 256 + threadIdx.x;  // 896*512
  if (idx >= 896*512) return;
  int k = idx & 511, n = idx >> 9;
  float v;
  if (n < 512) v = wq[(size_t)k*512 + n];
  else if (n < 640) v = wk[(size_t)k*128 + n - 512];
  else if (n < 768) v = wv[(size_t)k*128 + n - 640];
  else if (n < 792) v = wc[(size_t)k*24 + n - 768];
  else v = 0.f;
  u16 h = f2bf(v); hi[idx] = h; lo[idx] = f2bf(v - bf2f(h));
}

__global__ __launch_bounds__(256) void nsa_rope_tab(float* __restrict__ ct, float* __restrict__ st) {
  int idx = blockIdx.x * 256 + threadIdx.x;  // 4096*32
  if (idx >= 4096*32) return;
  int s = idx >> 5, i = idx & 31;
  float e = (float)(2*i) * (1.0f/64.0f);
  float inv = 1.0f / powf(10000.0f, e);
  float f = (float)s * inv;
  ct[idx] = cosf(f); st[idx] = sinf(f);
}

__global__ __launch_bounds__(256) void nsa_rope_k(const float* __restrict__ k32, const float* __restrict__ ct,
    const float* __restrict__ st, u16* __restrict__ kb) {
  int idx = blockIdx.x * 256 + threadIdx.x;  // 8*2*4096*32 = 2^21
  int d = idx & 31, s = (idx >> 5) & 4095, kh = (idx >> 17) & 1, b = idx >> 18;
  const float* kr = k32 + ((size_t)(b*4096 + s))*128 + kh*64;
  float t1 = kr[d], t2 = kr[d+32];
  float c = ct[s*32+d], sn = st[s*32+d];
  size_t ob = (((size_t)(b*2 + kh))*4096 + s)*64;
  kb[ob+d] = f2bf(t1*c - t2*sn);
  kb[ob+d+32] = f2bf(t2*c + t1*sn);
}

// v (B,S,KH,64 f32) -> vT (B,KH,64,S bf16)
__global__ __launch_bounds__(256) void nsa_vT(const float* __restrict__ v32, u16* __restrict__ vT) {
  int blk = blockIdx.x;  // 8*2*64
  int st = (blk & 63) * 64, kh = (blk >> 6) & 1, b = blk >> 7;
  __shared__ float tile[64][65];
  int t = threadIdx.x;
  int s = t >> 2, c0 = (t & 3) * 16;
  const float* src = v32 + ((size_t)(b*4096 + st + s))*128 + kh*64;
#pragma unroll
  for (int j = 0; j < 16; ++j) tile[s][c0+j] = src[c0+j];
  __syncthreads();
  int d = t >> 2, s0 = (t & 3) * 16;
  u16* dst = vT + (((size_t)(b*2 + kh))*64 + d)*4096 + st + s0;
#pragma unroll
  for (int j = 0; j < 16; ++j) dst[j] = f2bf(tile[s0+j][d]);
}

// kb/vb: (B,KH,nb,SEL*DH) = src + block pos emb, split hi/lo (lo optional)
__global__ __launch_bounds__(256) void nsa_kb(const float* __restrict__ src, const float* __restrict__ pe,
    u16* __restrict__ ohi, u16* __restrict__ olo) {
  int idx = blockIdx.x * 256 + threadIdx.x;  // 1024*4096 = 2^22
  int c = idx & 4095, m = idx >> 12;
  int sl = c >> 6, d = c & 63;
  int n = m & 63, kh = (m >> 6) & 1, b = m >> 7;
  int s = n*64 + sl;
  float v = src[((size_t)(b*4096 + s))*128 + kh*64 + d] + pe[(kh*64 + sl)*64 + d];
  u16 h = f2bf(v); ohi[idx] = h;
  if (olo) olo[idx] = f2bf(v - bf2f(h));
}

// transpose + split-convert: src f32 [K][N] -> dhi/dlo bf16 [N][K]
__global__ __launch_bounds__(256) void nsa_wT(const float* __restrict__ src, u16* __restrict__ dhi,
    u16* __restrict__ dlo, int K, int N) {
  __shared__ float tile[64][65];
  int k0 = blockIdx.x * 64, n0 = blockIdx.y * 64;
  int t = threadIdx.x, r = t >> 2, c0 = (t & 3) * 16;
#pragma unroll
  for (int j = 0; j < 16; ++j) tile[r][c0+j] = src[(size_t)(k0+r)*N + n0 + c0 + j];
  __syncthreads();
  size_t ob = (size_t)(n0 + r)*K + k0 + c0;
#pragma unroll
  for (int j = 0; j < 16; ++j) {
    float v = tile[c0+j][r];
    u16 h = f2bf(v); dhi[ob+j] = h;
    if (dlo) dlo[ob+j] = f2bf(v - bf2f(h));
  }
}

// init ck/cv f32 (B,KH,80,64): row0 = mem, rows 1..64 = bias2, rows 65..79 = 0
__global__ __launch_bounds__(256) void nsa_init_c(const float* __restrict__ mem, const float* __restrict__ b2,
    float* __restrict__ c32) {
  int idx = blockIdx.x * 256 + threadIdx.x;  // 8*2*80*64 = 81920
  if (idx >= 81920) return;
  int d = idx & 63, n = (idx >> 6) % 80, kh = (idx / (80*64)) & 1;
  c32[idx] = (n == 0) ? mem[kh*64 + d] : ((n <= 64) ? b2[d] : 0.f);
}

// deterministic reduce of split-K partials into c32 rows 1..64
__global__ __launch_bounds__(256) void nsa_red64(const float* __restrict__ part, float* __restrict__ c32) {
  int idx = blockIdx.x * 256 + threadIdx.x;  // 1024*64 = 65536
  int m = idx >> 6, d = idx & 63;
  float s = 0.f;
#pragma unroll
  for (int kc = 0; kc < 8; ++kc) s += part[((size_t)kc*1024 + m)*64 + d];
  int bkh = m >> 6, n = m & 63;
  c32[(((size_t)bkh)*80 + 1 + n)*64 + d] += s;
}

// ck f32 -> ck hi/lo (same layout); cv f32 -> cvT bf16 (B,KH,64,96 padded)
__global__ __launch_bounds__(256) void nsa_ckcv(const float* __restrict__ ck32, const float* __restrict__ cv32,
    u16* __restrict__ ckh, u16* __restrict__ ckl, u16* __restrict__ cvT) {
  int idx = blockIdx.x * 256 + threadIdx.x;
  if (idx < 81920) {
    float v = ck32[idx];
    u16 h = f2bf(v); ckh[idx] = h; ckl[idx] = f2bf(v - bf2f(h));
  } else if (idx < 81920 + 8*2*64*96) {
    int j = idx - 81920;
    int cc = j % 96, d = (j / 96) & 63, bkh = j / (96*64);
    float v = (cc < 80) ? cv32[((size_t)bkh*80 + cc)*64 + d] : 0.f;
    cvT[j] = f2bf(v);
  }
}

__global__ __launch_bounds__(256) void nsa_comb_bf(const float* __restrict__ c, u16* __restrict__ oh,
    u16* __restrict__ ol) {
  int i = blockIdx.x * 256 + threadIdx.x;  // 4194304 float4
  float4 v = ((const float4*)c)[i];
  u16 h0 = f2bf(v.x), l0 = f2bf(v.x - bf2f(h0));
  u16 h1 = f2bf(v.y), l1 = f2bf(v.y - bf2f(h1));
  u16 h2 = f2bf(v.z), l2 = f2bf(v.z - bf2f(h2));
  u16 h3 = f2bf(v.w), l3 = f2bf(v.w - bf2f(h3));
  unsigned long long ph = (unsigned long long)h0 | ((unsigned long long)h1 << 16) |
                          ((unsigned long long)h2 << 32) | ((unsigned long long)h3 << 48);
  unsigned long long pl = (unsigned long long)l0 | ((unsigned long long)l1 << 16) |
                          ((unsigned long long)l2 << 32) | ((unsigned long long)l3 << 48);
  ((unsigned long long*)oh)[i] = ph;
  ((unsigned long long*)ol)[i] = pl;
}

__global__ __launch_bounds__(256) void nsa_sentinel(float* __restrict__ o, int n, float val) {
  int i = blockIdx.x * 256 + threadIdx.x;
  if (i < n) o[i] = val;
}

// ================= GEMMs =================
// C = A @ B^T ; A: M x K bf16 (hi/lo), BT: N x K bf16 (hi/lo).
// 3-buffer pipeline, counted vmcnt (T3+T4), raw s_barrier; global_load_lds w16;
// both-sides XOR swizzle (linear LDS dest, swizzled global src chunk + swizzled read chunk).
// EPI 0: q-cols fused rotary -> split bf16 (B,H,S,D); k/v/gates routed f32.
// EPI 1: +bias, relu, (split) bf16 out.  EPI 2: f32 out (p_sin = out).
template<bool SPLIT, int EPI>
__global__ __launch_bounds__(256) void nsa_gemm(const u16* __restrict__ Ah, const u16* __restrict__ Al,
    const u16* __restrict__ Bh, const u16* __restrict__ Bl, int K, int N,
    const float* __restrict__ p_cos, float* __restrict__ p_sin,
    u16* __restrict__ out_hi, u16* __restrict__ out_lo,
    float* __restrict__ ok, float* __restrict__ ov, float* __restrict__ og) {
  constexpr int NB = SPLIT ? 4 : 2;          // tiles per buffer: Ah,Bh[,Al,Bl]
  __shared__ u16 sm[NB * 3 * 4096];          // 3 buffers, tile = 128x32 u16 = 4096
  const int t = threadIdx.x, w = t >> 6, l = t & 63;
  const int wm = w >> 1, wn = w & 1;
  const int m0 = blockIdx.x * 128, n0 = blockIdx.y * 128;
  const int row = l & 15;
  const int kc8 = ((l >> 4) ^ ((l >> 1) & 3)) * 8;   // swizzled read chunk
  const int gsc = ((l & 3) ^ ((l >> 3) & 3)) * 8;    // swizzled global source chunk
  const int sr = l >> 2;
  f32x4 acc[4][4];
#pragma unroll
  for (int a = 0; a < 4; ++a)
#pragma unroll
    for (int b = 0; b < 4; ++b) acc[a][b] = zero4();

  auto STAGE = [&](int buf, int kt) {
    int k0 = kt * 32;
    u16* base = sm + buf * NB * 4096;
#pragma unroll
    for (int s2 = 0; s2 < 2; ++s2) {
      int seg = w*2 + s2;                    // 0..7, 16 rows each
      int r = seg*16 + sr;
      size_t ga = (size_t)(m0 + r)*K + k0 + gsc;
      size_t gb = (size_t)(n0 + r)*K + k0 + gsc;
      GLDS16(&Ah[ga], base + seg*512);
      GLDS16(&Bh[gb], base + 4096 + seg*512);
      if (SPLIT) {
        GLDS16(&Al[ga], base + 2*4096 + seg*512);
        GLDS16(&Bl[gb], base + 3*4096 + seg*512);
      }
    }
  };
  // per-wave vmem instructions per STAGE: L = SPLIT ? 8 : 4

  const int nt = K >> 5;                     // >= 16 for all our shapes
  STAGE(0, 0);
  STAGE(1, 1);
  for (int kt = 0; kt < nt; ++kt) {
    if (kt + 2 < nt) {
      STAGE((kt + 2) % 3, kt + 2);
      if constexpr (SPLIT) asm volatile("s_waitcnt vmcnt(16)" ::: "memory");
      else                 asm volatile("s_waitcnt vmcnt(8)" ::: "memory");
    } else if (kt + 1 < nt) {
      if constexpr (SPLIT) asm volatile("s_waitcnt vmcnt(8)" ::: "memory");
      else                 asm volatile("s_waitcnt vmcnt(4)" ::: "memory");
    } else {
      asm volatile("s_waitcnt vmcnt(0)" ::: "memory");
    }
    __builtin_amdgcn_s_barrier();            // buf[kt%3] ready for all waves
    u16* bA  = sm + (kt % 3) * NB * 4096;
    u16* bB  = bA + 4096;
    u16* bAl = bA + 2*4096;
    u16* bBl = bA + 3*4096;
    bhalf8 af[4], afl[4];
#pragma unroll
    for (int mf = 0; mf < 4; ++mf) {
      af[mf] = LD8(&bA[(wm*64 + mf*16 + row)*32 + kc8]);
      if (SPLIT) afl[mf] = LD8(&bAl[(wm*64 + mf*16 + row)*32 + kc8]);
    }
#pragma unroll
    for (int nf = 0; nf < 4; ++nf) {
      bhalf8 bfh = LD8(&bB[(wn*64 + nf*16 + row)*32 + kc8]);
      bhalf8 bfl;
      if (SPLIT) bfl = LD8(&bBl[(wn*64 + nf*16 + row)*32 + kc8]);
#pragma unroll
      for (int mf = 0; mf < 4; ++mf) {
        acc[mf][nf] = MFMA(af[mf], bfh, acc[mf][nf]);
        if (SPLIT) {
          acc[mf][nf] = MFMA(af[mf], bfl, acc[mf][nf]);
          acc[mf][nf] = MFMA(afl[mf], bfh, acc[mf][nf]);
        }
      }
    }
    asm volatile("" ::: "memory");
    __builtin_amdgcn_s_barrier();            // all reads of buf[kt%3] done
    asm volatile("" ::: "memory");
  }
  if constexpr (EPI == 0) {
    if (n0 < 512) {
      // q columns: fused GPT-NeoX rotary. cols c (dd<32) pair with c+32 = acc[mf][nf+2].
#pragma unroll
      for (int mf = 0; mf < 4; ++mf)
#pragma unroll
        for (int i = 0; i < 4; ++i) {
          int r = m0 + wm*64 + mf*16 + (l >> 4)*4 + i;
          int s = r & 4095, b = r >> 12;
#pragma unroll
          for (int nf = 0; nf < 2; ++nf) {
            int c = n0 + wn*64 + nf*16 + (l & 15);
            int hq = c >> 6, dd = c & 31;
            float t1 = acc[mf][nf][i], t2 = acc[mf][nf+2][i];
            float cs = p_cos[s*32 + dd], sn = p_sin[s*32 + dd];
            float o1 = t1*cs - t2*sn, o2 = t2*cs + t1*sn;
            size_t ob = (((size_t)(b*8 + hq))*4096 + s)*64;
            u16 h1 = f2bf(o1); out_hi[ob+dd] = h1;    out_lo[ob+dd] = f2bf(o1 - bf2f(h1));
            u16 h2 = f2bf(o2); out_hi[ob+dd+32] = h2; out_lo[ob+dd+32] = f2bf(o2 - bf2f(h2));
          }
        }
    } else {
#pragma unroll
      for (int mf = 0; mf < 4; ++mf)
#pragma unroll
        for (int nf = 0; nf < 4; ++nf)
#pragma unroll
          for (int i = 0; i < 4; ++i) {
            int r = m0 + wm*64 + mf*16 + (l >> 4)*4 + i;
            int c = n0 + wn*64 + nf*16 + (l & 15);
            float v = acc[mf][nf][i];
            if (n0 == 512) ok[(size_t)r*128 + (c - 512)] = v;
            else if (n0 == 640) ov[(size_t)r*128 + (c - 640)] = v;
            else if (c < 792) og[(size_t)r*24 + (c - 768)] = 1.0f / (1.0f + expf(-v));
          }
    }
  } else {
#pragma unroll
    for (int mf = 0; mf < 4; ++mf)
#pragma unroll
      for (int nf = 0; nf < 4; ++nf)
#pragma unroll
        for (int i = 0; i < 4; ++i) {
          int r = m0 + wm*64 + mf*16 + (l >> 4)*4 + i;
          int c = n0 + wn*64 + nf*16 + (l & 15);
          float v = acc[mf][nf][i];
          if constexpr (EPI == 1) {
            v += p_cos[c];  // bias
            v = fmaxf(v, 0.0f);
            u16 h = f2bf(v);
            out_hi[(size_t)r*N + c] = h;
            if (SPLIT) out_lo[(size_t)r*N + c] = f2bf(v - bf2f(h));
          } else {
            p_sin[(size_t)r*N + c] = v;  // f32 out
          }
        }
  }
}

// M=1024, N=64, K=4096 split-K GEMM -> per-chunk partials (deterministic, no atomics)
template<bool SPLIT>
__global__ __launch_bounds__(256) void nsa_gemm64(const u16* __restrict__ Ah, const u16* __restrict__ Al,
    const u16* __restrict__ Bh, const u16* __restrict__ Bl, float* __restrict__ part) {
  constexpr int NB = SPLIT ? 4 : 2;
  __shared__ u16 sm[NB * 2 * 2048];          // 2 buffers, tile = 64x32 u16 = 2048
  const int t = threadIdx.x, w = t >> 6, l = t & 63;
  const int mt = blockIdx.x, kc = blockIdx.y;
  const int row = l & 15;
  const int kc8 = ((l >> 4) ^ ((l >> 1) & 3)) * 8;
  const int gsc = ((l & 3) ^ ((l >> 3) & 3)) * 8;
  const int sr = l >> 2;
  f32x4 acc[4];
#pragma unroll
  for (int a = 0; a < 4; ++a) acc[a] = zero4();

  auto STAGE = [&](int buf, int k0) {
    u16* base = sm + buf * NB * 2048;
    int r = w*16 + sr;
    size_t ga = (size_t)(mt*64 + r)*4096 + k0 + gsc;
    size_t gb = (size_t)r*4096 + k0 + gsc;
    GLDS16(&Ah[ga], base + w*512);
    GLDS16(&Bh[gb], base + 2048 + w*512);
    if (SPLIT) {
      GLDS16(&Al[ga], base + 2*2048 + w*512);
      GLDS16(&Bl[gb], base + 3*2048 + w*512);
    }
  };

  STAGE(0, kc*512);
  __syncthreads();
  int cur = 0;
  for (int kt = 0; kt < 16; ++kt) {
    if (kt + 1 < 16) STAGE(cur ^ 1, kc*512 + (kt + 1) * 32);
    u16* bA  = sm + cur * NB * 2048;
    u16* bB  = bA + 2048;
    u16* bAl = bA + 2*2048;
    u16* bBl = bA + 3*2048;
    bhalf8 a = LD8(&bA[(w*16 + row)*32 + kc8]);
    bhalf8 al;
    if (SPLIT) al = LD8(&bAl[(w*16 + row)*32 + kc8]);
#pragma unroll
    for (int nf = 0; nf < 4; ++nf) {
      bhalf8 b = LD8(&bB[(nf*16 + row)*32 + kc8]);
      bhalf8 bl;
      if (SPLIT) bl = LD8(&bBl[(nf*16 + row)*32 + kc8]);
      acc[nf] = MFMA(a, b, acc[nf]);
      if (SPLIT) {
        acc[nf] = MFMA(a, bl, acc[nf]);
        acc[nf] = MFMA(al, b, acc[nf]);
      }
    }
    __syncthreads();
    cur ^= 1;
  }
#pragma unroll
  for (int nf = 0; nf < 4; ++nf)
#pragma unroll
    for (int i = 0; i < 4; ++i) {
      int m = mt*64 + w*16 + (l >> 4)*4 + i;
      int d = nf*16 + (l & 15);
      part[((size_t)kc*1024 + m)*64 + d] = acc[nf][i];
    }
}

// ================= attention =================

// compressed: per (b,kh,g,qblk): 64 q x 65 keys (pad 80), split QK^T; writes gated cout + imp partials
__global__ __launch_bounds__(256) void nsa_attn_comp(const u16* __restrict__ qrh, const u16* __restrict__ qrl,
    const u16* __restrict__ ckh, const u16* __restrict__ ckl, const u16* __restrict__ cvT,
    const float* __restrict__ g32, float* __restrict__ comb, float* __restrict__ imp) {
  __shared__ u16 smem[27392];
  __shared__ float sImp[4 * 80];
  u16* sQh = smem;            // 64*72
  u16* sQl = smem + 4608;     // 64*72
  u16* sP  = smem;            // alias (64*104), used after QK
  u16* sKh = smem + 9216;     // 80*72
  u16* sKl = smem + 14976;    // 80*72
  u16* sVT = smem + 20736;    // 64*104
  const int t = threadIdx.x, w = t >> 6, l = t & 63;
  const int bid = blockIdx.x;
  const int qt = bid & 63, g = (bid >> 6) & 3, kh = (bid >> 8) & 1, b = bid >> 9;
  const int row = l & 15, kg = (l >> 4) * 8;
  size_t qbase = ((size_t)((b*2 + kh)*4 + g)*4096 + qt*64) * 64;
  size_t kbase = (size_t)(b*2 + kh) * 80 * 64;
  size_t vbase = (size_t)(b*2 + kh) * 64 * 96;
  for (int e = t; e < 512; e += 256) {
    int r = e >> 3, c = (e & 7) * 8;
    *(int4*)&sQh[r*72 + c] = *(const int4*)&qrh[qbase + r*64 + c];
    *(int4*)&sQl[r*72 + c] = *(const int4*)&qrl[qbase + r*64 + c];
  }
  for (int e = t; e < 640; e += 256) {
    int r = e >> 3, c = (e & 7) * 8;
    *(int4*)&sKh[r*72 + c] = *(const int4*)&ckh[kbase + r*64 + c];
    *(int4*)&sKl[r*72 + c] = *(const int4*)&ckl[kbase + r*64 + c];
  }
  for (int e = t; e < 768; e += 256) {
    int r = e / 12, ch = e % 12;
    *(int4*)&sVT[r*104 + ch*8] = *(const int4*)&cvT[vbase + (size_t)r*96 + ch*8];
  }
  __syncthreads();
  f32x4 sc[5];
#pragma unroll
  for (int nf = 0; nf < 5; ++nf) sc[nf] = zero4();
#pragma unroll
  for (int kk = 0; kk < 2; ++kk) {
    bhalf8 ah = LD8(&sQh[(w*16 + row)*72 + kk*32 + kg]);
    bhalf8 al = LD8(&sQl[(w*16 + row)*72 + kk*32 + kg]);
#pragma unroll
    for (int nf = 0; nf < 5; ++nf) {
      bhalf8 bh = LD8(&sKh[(nf*16 + row)*72 + kk*32 + kg]);
      bhalf8 bl = LD8(&sKl[(nf*16 + row)*72 + kk*32 + kg]);
      sc[nf] = MFMA(ah, bh, sc[nf]);
      sc[nf] = MFMA(ah, bl, sc[nf]);
      sc[nf] = MFMA(al, bh, sc[nf]);
    }
  }
  float mx[4] = {-1e30f, -1e30f, -1e30f, -1e30f};
#pragma unroll
  for (int nf = 0; nf < 5; ++nf)
#pragma unroll
    for (int i = 0; i < 4; ++i) {
      int col = nf*16 + (l & 15);
      float v = (col < 65) ? sc[nf][i] * 0.125f : -1e30f;
      sc[nf][i] = v;
      mx[i] = fmaxf(mx[i], v);
    }
#pragma unroll
  for (int i = 0; i < 4; ++i)
#pragma unroll
    for (int o = 1; o < 16; o <<= 1) mx[i] = fmaxf(mx[i], __shfl_xor(mx[i], o));
  float sum[4] = {0.f, 0.f, 0.f, 0.f};
#pragma unroll
  for (int nf = 0; nf < 5; ++nf)
#pragma unroll
    for (int i = 0; i < 4; ++i) {
      int col = nf*16 + (l & 15);
      float p = (col < 65) ? expf(sc[nf][i] - mx[i]) : 0.f;
      sc[nf][i] = p;
      sum[i] += p;
    }
#pragma unroll
  for (int i = 0; i < 4; ++i)
#pragma unroll
    for (int o = 1; o < 16; o <<= 1) sum[i] += __shfl_xor(sum[i], o);
  float inv[4];
#pragma unroll
  for (int i = 0; i < 4; ++i) inv[i] = 1.0f / sum[i];
  __syncthreads();  // all QK reads of sQ done; sP may alias it now
#pragma unroll
  for (int nf = 0; nf < 5; ++nf)
#pragma unroll
    for (int i = 0; i < 4; ++i)
      sP[(w*16 + (l >> 4)*4 + i)*104 + nf*16 + (l & 15)] = f2bf(sc[nf][i] * inv[i]);
#pragma unroll
  for (int i = 0; i < 4; ++i)
    sP[(w*16 + (l >> 4)*4 + i)*104 + 80 + (l & 15)] = 0;  // zero pad cols 80..95
#pragma unroll
  for (int nf = 0; nf < 5; ++nf) {
    float cs = 0.f;
#pragma unroll
    for (int i = 0; i < 4; ++i) cs += sc[nf][i] * inv[i];
    cs += __shfl_xor(cs, 16);
    cs += __shfl_xor(cs, 32);
    if (l < 16) sImp[w*80 + nf*16 + l] = cs;
  }
  __syncthreads();
  if (t < 64) {
    int n = t + 1;
    float v = sImp[n] + sImp[80 + n] + sImp[160 + n] + sImp[240 + n];
    imp[((size_t)((b*2 + kh)*4 + g)*64 + qt)*64 + t] = v * (1.0f/256.0f);
  }
  f32x4 ov[4];
#pragma unroll
  for (int nf = 0; nf < 4; ++nf) ov[nf] = zero4();
#pragma unroll
  for (int kk = 0; kk < 3; ++kk) {
    bhalf8 a = LD8(&sP[(w*16 + row)*104 + kk*32 + kg]);
#pragma unroll
    for (int nf = 0; nf < 4; ++nf) {
      bhalf8 bv = LD8(&sVT[(nf*16 + row)*104 + kk*32 + kg]);
      ov[nf] = MFMA(a, bv, ov[nf]);
    }
  }
  int hq = kh*4 + g;
#pragma unroll
  for (int i = 0; i < 4; ++i) {
    int q = qt*64 + w*16 + (l >> 4)*4 + i;
    float gate = g32[((size_t)b*4096 + q)*24 + hq*3 + 0];
#pragma unroll
    for (int nf = 0; nf < 4; ++nf) {
      int d = nf*16 + (l & 15);
      comb[(((size_t)b*4096 + q)*8 + hq)*64 + d] = gate * ov[nf][i];
    }
  }
}

__global__ __launch_bounds__(64) void nsa_top2(const float* __restrict__ imp, int* __restrict__ sel) {
  int blk = blockIdx.x;  // (b*2+kh)*64 + qt
  int l = threadIdx.x;
  int bkh = blk >> 6, qt = blk & 63;
  float v = 0.f;
#pragma unroll
  for (int g = 0; g < 4; ++g) v += imp[(((size_t)bkh*4 + g)*64 + qt)*64 + l];
  float v1 = v; int i1 = l;
#pragma unroll
  for (int o = 1; o < 64; o <<= 1) {
    float ovv = __shfl_xor(v1, o); int oi = __shfl_xor(i1, o);
    if (ovv > v1 || (ovv == v1 && oi < i1)) { v1 = ovv; i1 = oi; }
  }
  float v2 = (l == i1) ? -3.0e38f : v; int i2 = l;
#pragma unroll
  for (int o = 1; o < 64; o <<= 1) {
    float ovv = __shfl_xor(v2, o); int oi = __shfl_xor(i2, o);
    if (ovv > v2 || (ovv == v2 && oi < i2)) { v2 = ovv; i2 = oi; }
  }
  if (l == 0) { sel[blk*2 + 0] = i1; sel[blk*2 + 1] = i2; }
}

// fine: per (b,kh,qblk): 4 g-heads of 64 q x 192 keys ([sel0, sel1, own])
__global__ __launch_bounds__(256) void nsa_attn_fine(const u16* __restrict__ qrh, const u16* __restrict__ kr,
    const u16* __restrict__ vT, const int* __restrict__ sel, const float* __restrict__ g32,
    float* __restrict__ comb) {
  __shared__ u16 smem[31232];
  u16* sK  = smem;            // 192*72 = 13824 (aliased by sP 64*200 after QK)
  u16* sP  = smem;
  u16* sVT = smem + 13824;    // 64*200
  u16* sQ  = smem + 26624;    // 64*72
  const int t = threadIdx.x, w = t >> 6, l = t & 63;
  const int bid = blockIdx.x;
  const int qt = bid & 63, kh = (bid >> 6) & 1, b = bid >> 7;
  const int row = l & 15, kg = (l >> 4) * 8;
  const int s0 = sel[bid*2 + 0] & 63, s1 = sel[bid*2 + 1] & 63;
  size_t kvb = (size_t)(b*2 + kh) * 4096 * 64;
  size_t vtb = (size_t)(b*2 + kh) * 64 * 4096;
  for (int e = t; e < 1536; e += 256) {  // VT: 64 rows x 24 chunks
    int r = e / 24, ch = e % 24;
    int n0 = ch * 8, bi = n0 >> 6;
    int blkid = (bi == 0) ? s0 : ((bi == 1) ? s1 : qt);
    int sidx = blkid*64 + (n0 & 63);
    *(int4*)&sVT[r*200 + n0] = *(const int4*)&vT[vtb + (size_t)r*4096 + sidx];
  }
  for (int g = 0; g < 4; ++g) {
    __syncthreads();
    for (int e = t; e < 1536; e += 256) {  // K: 192 rows x 8 chunks
      int r = e >> 3, c = (e & 7) * 8;
      int bi = r >> 6;
      int blkid = (bi == 0) ? s0 : ((bi == 1) ? s1 : qt);
      int sidx = blkid*64 + (r & 63);
      *(int4*)&sK[r*72 + c] = *(const int4*)&kr[kvb + (size_t)sidx*64 + c];
    }
    size_t qbase = ((size_t)((b*2 + kh)*4 + g)*4096 + qt*64) * 64;
    for (int e = t; e < 512; e += 256) {
      int r = e >> 3, c = (e & 7) * 8;
      *(int4*)&sQ[r*72 + c] = *(const int4*)&qrh[qbase + r*64 + c];
    }
    __syncthreads();
    f32x4 sc[12];
#pragma unroll
    for (int nf = 0; nf < 12; ++nf) sc[nf] = zero4();
#pragma unroll
    for (int kk = 0; kk < 2; ++kk) {
      bhalf8 a = LD8(&sQ[(w*16 + row)*72 + kk*32 + kg]);
#pragma unroll
      for (int nf = 0; nf < 12; ++nf) {
        bhalf8 bk = LD8(&sK[(nf*16 + row)*72 + kk*32 + kg]);
        sc[nf] = MFMA(a, bk, sc[nf]);
      }
    }
    float mx[4] = {-1e30f, -1e30f, -1e30f, -1e30f};
#pragma unroll
    for (int nf = 0; nf < 12; ++nf)
#pragma unroll
      for (int i = 0; i < 4; ++i) {
        float v = sc[nf][i] * 0.125f;
        sc[nf][i] = v;
        mx[i] = fmaxf(mx[i], v);
      }
#pragma unroll
    for (int i = 0; i < 4; ++i)
#pragma unroll
      for (int o = 1; o < 16; o <<= 1) mx[i] = fmaxf(mx[i], __shfl_xor(mx[i], o));
    float sum[4] = {0.f, 0.f, 0.f, 0.f};
#pragma unroll
    for (int nf = 0; nf < 12; ++nf)
#pragma unroll
      for (int i = 0; i < 4; ++i) {
        float p = expf(sc[nf][i] - mx[i]);
        sc[nf][i] = p;
        sum[i] += p;
      }
#pragma unroll
    for (int i = 0; i < 4; ++i)
#pragma unroll
      for (int o = 1; o < 16; o <<= 1) sum[i] += __shfl_xor(sum[i], o);
    float inv[4];
#pragma unroll
    for (int i = 0; i < 4; ++i) inv[i] = 1.0f / sum[i];
    __syncthreads();  // all done reading sK -> sP may alias
#pragma unroll
    for (int nf = 0; nf < 12; ++nf)
#pragma unroll
      for (int i = 0; i < 4; ++i)
        sP[(w*16 + (l >> 4)*4 + i)*200 + nf*16 + (l & 15)] = f2bf(sc[nf][i] * inv[i]);
    __syncthreads();
    f32x4 ovv[4];
#pragma unroll
    for (int nf = 0; nf < 4; ++nf) ovv[nf] = zero4();
#pragma unroll
    for (int kk = 0; kk < 6; ++kk) {
      bhalf8 a = LD8(&sP[(w*16 + row)*200 + kk*32 + kg]);
#pragma unroll
      for (int nf = 0; nf < 4; ++nf) {
        bhalf8 bv = LD8(&sVT[(nf*16 + row)*200 + kk*32 + kg]);
        ovv[nf] = MFMA(a, bv, ovv[nf]);
      }
    }
    int hq = kh*4 + g;
#pragma unroll
    for (int i = 0; i < 4; ++i) {
      int q = qt*64 + w*16 + (l >> 4)*4 + i;
      float gate = g32[((size_t)b*4096 + q)*24 + hq*3 + 1];
#pragma unroll
      for (int nf = 0; nf < 4; ++nf) {
        int d = nf*16 + (l & 15);
        size_t oi = (((size_t)b*4096 + q)*8 + hq)*64 + d;
        comb[oi] += gate * ovv[nf][i];
      }
    }
  }
}

// sliding: per (b,h,ball): K/V loaded once, both 64-q halves of the 128-ball
__global__ __launch_bounds__(256) void nsa_attn_slide(const u16* __restrict__ qrh, const u16* __restrict__ kr,
    const u16* __restrict__ vT, const float* __restrict__ g32, float* __restrict__ comb) {
  __shared__ u16 smem[31232];
  u16* sK  = smem;            // 128*72 = 9216
  u16* sVT = smem + 9216;     // 64*136 = 8704
  u16* sQ  = smem + 17920;    // 64*72 = 4608
  u16* sP  = smem + 22528;    // 64*136 = 8704
  const int t = threadIdx.x, w = t >> 6, l = t & 63;
  const int bid = blockIdx.x;  // 8*8*32
  const int ball = bid & 31, hh = (bid >> 5) & 7, b = bid >> 8;
  const int kh = hh >> 2;
  const int row = l & 15, kg = (l >> 4) * 8;
  const int ks0 = ball * 128;
  size_t kvb = (size_t)(b*2 + kh) * 4096 * 64;
  size_t vtb = (size_t)(b*2 + kh) * 64 * 4096;
  for (int e = t; e < 1024; e += 256) {
    int r = e >> 3, c = (e & 7) * 8;
    *(int4*)&sK[r*72 + c] = *(const int4*)&kr[kvb + (size_t)(ks0 + r)*64 + c];
  }
  for (int e = t; e < 1024; e += 256) {
    int r = e >> 4, ch = e & 15;
    *(int4*)&sVT[r*136 + ch*8] = *(const int4*)&vT[vtb + (size_t)r*4096 + ks0 + ch*8];
  }
  for (int qh = 0; qh < 2; ++qh) {
    int qt = ball*2 + qh;
    __syncthreads();  // prev PV done (sP), prev QK done (sQ); K/VT ready on iter 0 w/ next sync
    size_t qbase = ((size_t)(b*8 + hh)*4096 + qt*64) * 64;
    for (int e = t; e < 512; e += 256) {
      int r = e >> 3, c = (e & 7) * 8;
      *(int4*)&sQ[r*72 + c] = *(const int4*)&qrh[qbase + r*64 + c];
    }
    __syncthreads();
    f32x4 sc[8];
#pragma unroll
    for (int nf = 0; nf < 8; ++nf) sc[nf] = zero4();
#pragma unroll
    for (int kk = 0; kk < 2; ++kk) {
      bhalf8 a = LD8(&sQ[(w*16 + row)*72 + kk*32 + kg]);
#pragma unroll
      for (int nf = 0; nf < 8; ++nf) {
        bhalf8 bk = LD8(&sK[(nf*16 + row)*72 + kk*32 + kg]);
        sc[nf] = MFMA(a, bk, sc[nf]);
      }
    }
    float mx[4] = {-1e30f, -1e30f, -1e30f, -1e30f};
#pragma unroll
    for (int nf = 0; nf < 8; ++nf)
#pragma unroll
      for (int i = 0; i < 4; ++i) {
        float v = sc[nf][i] * 0.125f;
        sc[nf][i] = v;
        mx[i] = fmaxf(mx[i], v);
      }
#pragma unroll
    for (int i = 0; i < 4; ++i)
#pragma unroll
      for (int o = 1; o < 16; o <<= 1) mx[i] = fmaxf(mx[i], __shfl_xor(mx[i], o));
    float sum[4] = {0.f, 0.f, 0.f, 0.f};
#pragma unroll
    for (int nf = 0; nf < 8; ++nf)
#pragma unroll
      for (int i = 0; i < 4; ++i) {
        float p = expf(sc[nf][i] - mx[i]);
        sc[nf][i] = p;
        sum[i] += p;
      }
#pragma unroll
    for (int i = 0; i < 4; ++i)
#pragma unroll
      for (int o = 1; o < 16; o <<= 1) sum[i] += __shfl_xor(sum[i], o);
    float inv[4];
#pragma unroll
    for (int i = 0; i < 4; ++i) inv[i] = 1.0f / sum[i];
#pragma unroll
    for (int nf = 0; nf < 8; ++nf)
#pragma unroll
      for (int i = 0; i < 4; ++i)
        sP[(w*16 + (l >> 4)*4 + i)*136 + nf*16 + (l & 15)] = f2bf(sc[nf][i] * inv[i]);
    __syncthreads();
    f32x4 ovv[4];
#pragma unroll
    for (int nf = 0; nf < 4; ++nf) ovv[nf] = zero4();
#pragma unroll
    for (int kk = 0; kk < 4; ++kk) {
      bhalf8 a = LD8(&sP[(w*16 + row)*136 + kk*32 + kg]);
#pragma unroll
      for (int nf = 0; nf < 4; ++nf) {
        bhalf8 bv = LD8(&sVT[(nf*16 + row)*136 + kk*32 + kg]);
        ovv[nf] = MFMA(a, bv, ovv[nf]);
      }
    }
#pragma unroll
    for (int i = 0; i < 4; ++i) {
      int q = qt*64 + w*16 + (l >> 4)*4 + i;
      float gate = g32[((size_t)b*4096 + q)*24 + hh*3 + 2];
#pragma unroll
      for (int nf = 0; nf < 4; ++nf) {
        int d = nf*16 + (l & 15);
        size_t oi = (((size_t)b*4096 + q)*8 + hh)*64 + d;
        comb[oi] += gate * ovv[nf][i];
      }
    }
  }
}

// ================= launch =================

extern "C" void kernel_launch(void* const* d_in, const int* in_sizes, int n_in,
                              void* d_out, int out_size, void* d_ws, size_t ws_size,
                              hipStream_t stream) {
  const float* x     = (const float*)d_in[0];
  const float* pos   = (const float*)d_in[1];
  const float* pe_w  = (const float*)d_in[2];
  const float* pe_b  = (const float*)d_in[3];
  const float* gamma = (const float*)d_in[4];
  const float* wq    = (const float*)d_in[5];
  const float* wk    = (const float*)d_in[6];
  const float* wv    = (const float*)d_in[7];
  const float* k_pos = (const float*)d_in[8];
  const float* v_pos = (const float*)d_in[9];
  const float* k_w1  = (const float*)d_in[10];
  const float* k_b1  = (const float*)d_in[11];
  const float* k_w2  = (const float*)d_in[12];
  const float* k_b2  = (const float*)d_in[13];
  const float* v_w1  = (const float*)d_in[14];
  const float* v_b1  = (const float*)d_in[15];
  const float* v_w2  = (const float*)d_in[16];
  const float* v_b2  = (const float*)d_in[17];
  const float* mem_k = (const float*)d_in[18];
  const float* mem_v = (const float*)d_in[19];
  const float* w_cmb = (const float*)d_in[20];
  const float* w_out = (const float*)d_in[21];
  float* out = (float*)d_out;
  char* ws = (char*)d_ws;

  // ---- region plan (aliased lifetimes), ~203.5 MiB total ----
  size_t off = 0;
  auto A = [&](size_t b) { size_t o = off; off += (b + 255) & ~(size_t)255; return o; };
  const size_t oR1 = A(67108864);   // h_hi|h_lo -> w1h|w1l -> comb
  const size_t oR2 = A(67108864);   // qrh|qrl -> cbh|cbl
  const size_t oR4 = A(16777216);   // k32 -> th|tl
  const size_t oR5 = A(16777216);   // v32
  const size_t oR6 = A(16777216);   // kbh|kbl (k then v)
  const size_t oR7 = A(16777216);   // kr|vT
  const size_t oR8 = A(3145728);    // g32
  const size_t oR9 = A(2097152);    // wch|wcl -> w2h|w2l|w2vh|w2vl
  const size_t o_cos = A(524288),  o_sin = A(524288);
  const size_t o_pm  = A(8192);
  const size_t o_ck32 = A(327680), o_cv32 = A(327680);
  const size_t o_ckh = A(163840),  o_ckl = A(163840);
  const size_t o_cvT = A(196608);
  const size_t o_woh = A(524288),  o_wol = A(524288);
  const size_t o_imp = A(1048576);
  const size_t o_sel = A(8192);
  const size_t o_part = A(2097152);

  if (ws_size < off) {  // diagnostic: absmax will read ~ws_size in MiB
    nsa_sentinel<<<(out_size + 255)/256, 256, 0, stream>>>(out, out_size, (float)(ws_size >> 20));
    return;
  }

#define WP(T, o) ((T*)(ws + (o)))
  u16*  h_hi = WP(u16, oR1);           u16* h_lo = WP(u16, oR1 + 33554432);
  u16*  w1h  = WP(u16, oR1);           u16* w1l  = WP(u16, oR1 + 33554432);
  float* comb = WP(float, oR1);
  u16*  qrh  = WP(u16, oR2);           u16* qrl  = WP(u16, oR2 + 33554432);
  u16*  cbh  = WP(u16, oR2);           u16* cbl  = WP(u16, oR2 + 33554432);
  float* k32 = WP(float, oR4);
  u16*  th   = WP(u16, oR4);           u16* tl   = WP(u16, oR4 + 8388608);
  float* v32 = WP(float, oR5);
  u16*  kbh  = WP(u16, oR6);           u16* kbl  = WP(u16, oR6 + 8388608);
  u16*  krb  = WP(u16, oR7);           u16* vTb  = WP(u16, oR7 + 8388608);
  float* g32 = WP(float, oR8);
  u16*  wch  = WP(u16, oR9);           u16* wcl  = WP(u16, oR9 + 917504);
  u16*  w2h  = WP(u16, oR9);           u16* w2l  = WP(u16, oR9 + 524288);
  u16*  w2vh = WP(u16, oR9 + 1048576); u16* w2vl = WP(u16, oR9 + 1572864);
  float* cosb = WP(float, o_cos);      float* sinb = WP(float, o_sin);
  float* pm  = WP(float, o_pm);
  float* ck32 = WP(float, o_ck32);     float* cv32 = WP(float, o_cv32);
  u16*  ckh  = WP(u16, o_ckh);         u16* ckl  = WP(u16, o_ckl);
  u16*  cvT  = WP(u16, o_cvT);
  u16*  woh  = WP(u16, o_woh);         u16* wol  = WP(u16, o_wol);
  float* imp = WP(float, o_imp);
  int*  selp = WP(int, o_sel);
  float* part = WP(float, o_part);

  nsa_pos_mean<<<512, 64, 0, stream>>>(pos, pm);
  nsa_hnorm<<<32768, 256, 0, stream>>>(x, pos, pm, pe_w, pe_b, gamma, h_hi, h_lo);
  nsa_wcatT<<<1792, 256, 0, stream>>>(wq, wk, wv, w_cmb, wch, wcl);
  nsa_rope_tab<<<512, 256, 0, stream>>>(cosb, sinb);
  // projection + fused rotary-Q epilogue -> qrh/qrl, k32, v32, g32
  nsa_gemm<true, 0><<<dim3(256, 7), 256, 0, stream>>>(h_hi, h_lo, wch, wcl, 512, 896,
      cosb, sinb, qrh, qrl, k32, v32, g32);
  nsa_rope_k<<<8192, 256, 0, stream>>>(k32, cosb, sinb, krb);
  nsa_vT<<<1024, 256, 0, stream>>>(v32, vTb);
  // k compression MLP (split precision: feeds top-k selection)
  nsa_kb<<<16384, 256, 0, stream>>>(k32, k_pos, kbh, kbl);           // k32 dead after
  nsa_wT<<<dim3(64, 64), 256, 0, stream>>>(k_w1, w1h, w1l, 4096, 4096);  // h dead
  nsa_gemm<true, 1><<<dim3(8, 32), 256, 0, stream>>>(kbh, kbl, w1h, w1l, 4096, 4096,
      k_b1, nullptr, th, tl, nullptr, nullptr, nullptr);             // th/tl overwrite k32
  nsa_wT<<<dim3(64, 1), 256, 0, stream>>>(k_w2, w2h, w2l, 4096, 64); // wc dead
  nsa_init_c<<<320, 256, 0, stream>>>(mem_k, k_b2, ck32);
  nsa_gemm64<true><<<dim3(16, 8), 256, 0, stream>>>(th, tl, w2h, w2l, part);
  nsa_red64<<<256, 256, 0, stream>>>(part, ck32);
  // v compression MLP (plain bf16: values only, not selection-critical)
  nsa_kb<<<16384, 256, 0, stream>>>(v32, v_pos, kbh, nullptr);       // v32 dead after
  nsa_wT<<<dim3(64, 64), 256, 0, stream>>>(v_w1, w1h, nullptr, 4096, 4096);
  nsa_gemm<false, 1><<<dim3(8, 32), 256, 0, stream>>>(kbh, nullptr, w1h, nullptr, 4096, 4096,
      v_b1, nullptr, th, nullptr, nullptr, nullptr, nullptr);
  nsa_wT<<<dim3(64, 1), 256, 0, stream>>>(v_w2, w2vh, nullptr, 4096, 64);
  nsa_init_c<<<320, 256, 0, stream>>>(mem_v, v_b2, cv32);
  nsa_gemm64<false><<<dim3(16, 8), 256, 0, stream>>>(th, nullptr, w2vh, nullptr, part);
  nsa_red64<<<256, 256, 0, stream>>>(part, cv32);
  nsa_ckcv<<<704, 256, 0, stream>>>(ck32, cv32, ckh, ckl, cvT);
  // attention branches -> gated combine (comb overwrites w1 region)
  nsa_attn_comp<<<4096, 256, 0, stream>>>(qrh, qrl, ckh, ckl, cvT, g32, comb, imp);
  nsa_top2<<<1024, 64, 0, stream>>>(imp, selp);
  nsa_attn_fine<<<1024, 256, 0, stream>>>(qrh, krb, vTb, selp, g32, comb);
  nsa_attn_slide<<<2048, 256, 0, stream>>>(qrh, krb, vTb, g32, comb);
  // output projection (split; cbh/cbl overwrite qr region)
  nsa_comb_bf<<<16384, 256, 0, stream>>>(comb, cbh, cbl);
  nsa_wT<<<dim3(8, 8), 256, 0, stream>>>(w_out, woh, wol, 512, 512);
  nsa_gemm<true, 2><<<dim3(256, 4), 256, 0, stream>>>(cbh, cbl, woh, wol, 512, 512,
      nullptr, out, nullptr, nullptr, nullptr, nullptr, nullptr);
#undef WP
}

// Round 6
// 737.866 us; speedup vs baseline: 1.1573x; 1.1573x over previous
//
#include <hip/hip_runtime.h>
#include <stdint.h>

#define DEVI static __device__ __forceinline__
typedef unsigned short u16;
typedef __bf16 bhalf8 __attribute__((ext_vector_type(8)));
typedef float f32x4 __attribute__((ext_vector_type(4)));

DEVI u16 f2bf(float f) {
  union { float f; unsigned u; } v; v.f = f;
  unsigned r = v.u + 0x7FFFu + ((v.u >> 16) & 1u);
  return (u16)(r >> 16);
}
DEVI float bf2f(u16 h) {
  union { unsigned u; float f; } v; v.u = ((unsigned)h) << 16;
  return v.f;
}
DEVI f32x4 MFMA(bhalf8 a, bhalf8 b, f32x4 c) {
  return __builtin_amdgcn_mfma_f32_16x16x32_bf16(a, b, c, 0, 0, 0);
}
DEVI bhalf8 LD8(const u16* p) { return *(const bhalf8*)p; }
DEVI f32x4 zero4() { f32x4 z = {0.f, 0.f, 0.f, 0.f}; return z; }

// async global->LDS, 16B per lane, dest = wave-uniform base + lane*16
#define GLDS16(gp, lp) __builtin_amdgcn_global_load_lds( \
    (const __attribute__((address_space(1))) void*)(gp), \
    (__attribute__((address_space(3))) void*)(lp), 16, 0, 0)

// ================= prep / elementwise =================

__global__ __launch_bounds__(64) void nsa_pos_mean(const float* __restrict__ pos, float* __restrict__ pm) {
  int blk = blockIdx.x, l = threadIdx.x;
  const float* p = pos + (size_t)(blk * 64 + l) * 3;
  float a = p[0], b = p[1], c = p[2];
#pragma unroll
  for (int o = 32; o; o >>= 1) { a += __shfl_down(a, o); b += __shfl_down(b, o); c += __shfl_down(c, o); }
  if (l == 0) { pm[blk*3+0] = a * (1.f/64.f); pm[blk*3+1] = b * (1.f/64.f); pm[blk*3+2] = c * (1.f/64.f); }
}

__global__ __launch_bounds__(256) void nsa_hnorm(const float* __restrict__ x, const float* __restrict__ pos,
    const float* __restrict__ pm, const float* __restrict__ pew, const float* __restrict__ peb,
    const float* __restrict__ gamma, u16* __restrict__ hhi, u16* __restrict__ hlo) {
  int n = blockIdx.x, t = threadIdx.x;
  int blk = n >> 6;
  float r0 = pos[(size_t)n*3+0] - pm[blk*3+0];
  float r1 = pos[(size_t)n*3+1] - pm[blk*3+1];
  float r2 = pos[(size_t)n*3+2] - pm[blk*3+2];
  int c0 = t, c1 = t + 256;
  const float* xr = x + (size_t)n * 512;
  float v0 = xr[c0] + r0*pew[c0] + r1*pew[512+c0] + r2*pew[1024+c0] + peb[c0];
  float v1 = xr[c1] + r0*pew[c1] + r1*pew[512+c1] + r2*pew[1024+c1] + peb[c1];
  float ss = v0*v0 + v1*v1;
#pragma unroll
  for (int o = 32; o; o >>= 1) ss += __shfl_down(ss, o);
  __shared__ float red[4];
  if ((t & 63) == 0) red[t >> 6] = ss;
  __syncthreads();
  float rms = 1.0f / sqrtf((red[0]+red[1]+red[2]+red[3]) * (1.0f/512.0f) + 1e-6f);
  float h0 = v0 * rms * gamma[c0], h1 = v1 * rms * gamma[c1];
  u16 a0 = f2bf(h0); hhi[(size_t)n*512+c0] = a0; hlo[(size_t)n*512+c0] = f2bf(h0 - bf2f(a0));
  u16 a1 = f2bf(h1); hhi[(size_t)n*512+c1] = a1; hlo[(size_t)n*512+c1] = f2bf(h1 - bf2f(a1));
}

// WcatT[n][k], n<896: cols of [wq|wk|wv|w_combine|pad]
__global__ __launch_bounds__(256) void nsa_wcatT(const float* __restrict__ wq, const float* __restrict__ wk,
    const float* __restrict__ wv, const float* __restrict__ wc, u16* __restrict__ hi, u16* __restrict__ lo) {
  int idx = blockIdx.x * 256 + threadIdx.x;  // 896*512
  if (idx >= 896*512) return;
  int k = idx & 511, n = idx >> 9;
  float v;
  if (n < 512) v = wq[(size_t)k*512 + n];
  else if (n < 640) v = wk[(size_t)k*128 + n - 512];
  else if (n < 768) v = wv[(size_t)k*128 + n - 640];
  else if (n < 792) v = wc[(size_t)k*24 + n - 768];
  else v = 0.f;
  u16 h = f2bf(v); hi[idx] = h; lo[idx] = f2bf(v - bf2f(h));
}

__global__ __launch_bounds__(256) void nsa_rope_tab(float* __restrict__ ct, float* __restrict__ st) {
  int idx = blockIdx.x * 256 + threadIdx.x;  // 4096*32
  if (idx >= 4096*32) return;
  int s = idx >> 5, i = idx & 31;
  float e = (float)(2*i) * (1.0f/64.0f);
  float inv = 1.0f / powf(10000.0f, e);
  float f = (float)s * inv;
  ct[idx] = cosf(f); st[idx] = sinf(f);
}

__global__ __launch_bounds__(256) void nsa_rope_k(const float* __restrict__ k32, const float* __restrict__ ct,
    const float* __restrict__ st, u16* __restrict__ kb) {
  int idx = blockIdx.x * 256 + threadIdx.x;  // 8*2*4096*32 = 2^21
  int d = idx & 31, s = (idx >> 5) & 4095, kh = (idx >> 17) & 1, b = idx >> 18;
  const float* kr = k32 + ((size_t)(b*4096 + s))*128 + kh*64;
  float t1 = kr[d], t2 = kr[d+32];
  float c = ct[s*32+d], sn = st[s*32+d];
  size_t ob = (((size_t)(b*2 + kh))*4096 + s)*64;
  kb[ob+d] = f2bf(t1*c - t2*sn);
  kb[ob+d+32] = f2bf(t2*c + t1*sn);
}

// v (B,S,KH,64 f32) -> vT (B,KH,64,S bf16)
__global__ __launch_bounds__(256) void nsa_vT(const float* __restrict__ v32, u16* __restrict__ vT) {
  int blk = blockIdx.x;  // 8*2*64
  int st = (blk & 63) * 64, kh = (blk >> 6) & 1, b = blk >> 7;
  __shared__ float tile[64][65];
  int t = threadIdx.x;
  int s = t >> 2, c0 = (t & 3) * 16;
  const float* src = v32 + ((size_t)(b*4096 + st + s))*128 + kh*64;
#pragma unroll
  for (int j = 0; j < 16; ++j) tile[s][c0+j] = src[c0+j];
  __syncthreads();
  int d = t >> 2, s0 = (t & 3) * 16;
  u16* dst = vT + (((size_t)(b*2 + kh))*64 + d)*4096 + st + s0;
#pragma unroll
  for (int j = 0; j < 16; ++j) dst[j] = f2bf(tile[s0+j][d]);
}

// kb/vb: (B,KH,nb,SEL*DH) = src + block pos emb, split hi/lo (lo optional)
__global__ __launch_bounds__(256) void nsa_kb(const float* __restrict__ src, const float* __restrict__ pe,
    u16* __restrict__ ohi, u16* __restrict__ olo) {
  int idx = blockIdx.x * 256 + threadIdx.x;  // 1024*4096 = 2^22
  int c = idx & 4095, m = idx >> 12;
  int sl = c >> 6, d = c & 63;
  int n = m & 63, kh = (m >> 6) & 1, b = m >> 7;
  int s = n*64 + sl;
  float v = src[((size_t)(b*4096 + s))*128 + kh*64 + d] + pe[(kh*64 + sl)*64 + d];
  u16 h = f2bf(v); ohi[idx] = h;
  if (olo) olo[idx] = f2bf(v - bf2f(h));
}

// transpose + split-convert: src f32 [K][N] -> dhi/dlo bf16 [N][K]
__global__ __launch_bounds__(256) void nsa_wT(const float* __restrict__ src, u16* __restrict__ dhi,
    u16* __restrict__ dlo, int K, int N) {
  __shared__ float tile[64][65];
  int k0 = blockIdx.x * 64, n0 = blockIdx.y * 64;
  int t = threadIdx.x, r = t >> 2, c0 = (t & 3) * 16;
#pragma unroll
  for (int j = 0; j < 16; ++j) tile[r][c0+j] = src[(size_t)(k0+r)*N + n0 + c0 + j];
  __syncthreads();
  size_t ob = (size_t)(n0 + r)*K + k0 + c0;
#pragma unroll
  for (int j = 0; j < 16; ++j) {
    float v = tile[c0+j][r];
    u16 h = f2bf(v); dhi[ob+j] = h;
    if (dlo) dlo[ob+j] = f2bf(v - bf2f(h));
  }
}

// init ck/cv f32 (B,KH,80,64): row0 = mem, rows 1..64 = bias2, rows 65..79 = 0
__global__ __launch_bounds__(256) void nsa_init_c(const float* __restrict__ mem, const float* __restrict__ b2,
    float* __restrict__ c32) {
  int idx = blockIdx.x * 256 + threadIdx.x;  // 8*2*80*64 = 81920
  if (idx >= 81920) return;
  int d = idx & 63, n = (idx >> 6) % 80, kh = (idx / (80*64)) & 1;
  c32[idx] = (n == 0) ? mem[kh*64 + d] : ((n <= 64) ? b2[d] : 0.f);
}

// deterministic reduce of split-K partials into c32 rows 1..64
__global__ __launch_bounds__(256) void nsa_red64(const float* __restrict__ part, float* __restrict__ c32) {
  int idx = blockIdx.x * 256 + threadIdx.x;  // 1024*64 = 65536
  int m = idx >> 6, d = idx & 63;
  float s = 0.f;
#pragma unroll
  for (int kc = 0; kc < 8; ++kc) s += part[((size_t)kc*1024 + m)*64 + d];
  int bkh = m >> 6, n = m & 63;
  c32[(((size_t)bkh)*80 + 1 + n)*64 + d] += s;
}

// MLP split-K fuse: sum 2 partial slices + bias + relu -> bf16 hi (and lo if SPLIT)
template<bool SPLIT>
__global__ __launch_bounds__(256) void nsa_mlp_fuse(const float* __restrict__ part,
    const float* __restrict__ bias, u16* __restrict__ oh, u16* __restrict__ ol) {
  size_t i = ((size_t)blockIdx.x * 256 + threadIdx.x) * 4;  // 1024*4096 elems, grid 4096
  int c = (int)(i & 4095);
  float4 a = *(const float4*)&part[i];
  float4 b = *(const float4*)&part[(size_t)4194304 + i];
  float v0 = fmaxf(a.x + b.x + bias[c+0], 0.f);
  float v1 = fmaxf(a.y + b.y + bias[c+1], 0.f);
  float v2 = fmaxf(a.z + b.z + bias[c+2], 0.f);
  float v3 = fmaxf(a.w + b.w + bias[c+3], 0.f);
  u16 h0 = f2bf(v0), h1 = f2bf(v1), h2 = f2bf(v2), h3 = f2bf(v3);
  ((unsigned long long*)oh)[i >> 2] = (unsigned long long)h0 | ((unsigned long long)h1 << 16) |
                                      ((unsigned long long)h2 << 32) | ((unsigned long long)h3 << 48);
  if (SPLIT) {
    u16 l0 = f2bf(v0 - bf2f(h0)), l1 = f2bf(v1 - bf2f(h1));
    u16 l2 = f2bf(v2 - bf2f(h2)), l3 = f2bf(v3 - bf2f(h3));
    ((unsigned long long*)ol)[i >> 2] = (unsigned long long)l0 | ((unsigned long long)l1 << 16) |
                                        ((unsigned long long)l2 << 32) | ((unsigned long long)l3 << 48);
  }
}

// ck f32 -> ck hi/lo (same layout); cv f32 -> cvT bf16 (B,KH,64,96 padded)
__global__ __launch_bounds__(256) void nsa_ckcv(const float* __restrict__ ck32, const float* __restrict__ cv32,
    u16* __restrict__ ckh, u16* __restrict__ ckl, u16* __restrict__ cvT) {
  int idx = blockIdx.x * 256 + threadIdx.x;
  if (idx < 81920) {
    float v = ck32[idx];
    u16 h = f2bf(v); ckh[idx] = h; ckl[idx] = f2bf(v - bf2f(h));
  } else if (idx < 81920 + 8*2*64*96) {
    int j = idx - 81920;
    int cc = j % 96, d = (j / 96) & 63, bkh = j / (96*64);
    float v = (cc < 80) ? cv32[((size_t)bkh*80 + cc)*64 + d] : 0.f;
    cvT[j] = f2bf(v);
  }
}

// comb f32 -> bf16 hi only (final GEMM is plain bf16)
__global__ __launch_bounds__(256) void nsa_comb_bf(const float* __restrict__ c, u16* __restrict__ oh) {
  int i = blockIdx.x * 256 + threadIdx.x;  // 4194304 float4
  float4 v = ((const float4*)c)[i];
  u16 h0 = f2bf(v.x), h1 = f2bf(v.y), h2 = f2bf(v.z), h3 = f2bf(v.w);
  ((unsigned long long*)oh)[i] = (unsigned long long)h0 | ((unsigned long long)h1 << 16) |
                                 ((unsigned long long)h2 << 32) | ((unsigned long long)h3 << 48);
}

__global__ __launch_bounds__(256) void nsa_sentinel(float* __restrict__ o, int n, float val) {
  int i = blockIdx.x * 256 + threadIdx.x;
  if (i < n) o[i] = val;
}

// ================= GEMMs =================
// C = A @ B^T ; A: M x K bf16 (hi/lo), BT: N x K bf16 (hi/lo).
// 2-phase double-buffered LDS (R4 structure, 2 blocks/CU for split), global_load_lds w16,
// both-sides XOR swizzle, XCD-aware block swizzle, optional split-K via blockIdx.z.
// EPI 0: q-cols fused rotary -> split bf16 (B,H,S,D); k/v/gates routed f32.
// EPI 2: f32 out (p_sin = out).  EPI 3: f32 partials to p_sin[z][M][N].
template<bool SPLIT, int EPI>
__global__ __launch_bounds__(256) void nsa_gemm(const u16* __restrict__ Ah, const u16* __restrict__ Al,
    const u16* __restrict__ Bh, const u16* __restrict__ Bl, int K, int N,
    const float* __restrict__ p_cos, float* __restrict__ p_sin,
    u16* __restrict__ out_hi, u16* __restrict__ out_lo,
    float* __restrict__ ok, float* __restrict__ ov, float* __restrict__ og) {
  constexpr int NB = SPLIT ? 4 : 2;          // tiles per buffer: Ah,Bh[,Al,Bl]
  __shared__ u16 sm[NB * 2 * 4096];          // 2 buffers, tile = 128x32 u16 = 4096
  const int t = threadIdx.x, w = t >> 6, l = t & 63;
  const int wm = w >> 1, wn = w & 1;
  // XCD-aware swizzle (all launches have nwg % 8 == 0)
  const int MBn = gridDim.x;
  const int nwg = MBn * gridDim.y;
  const int bid = blockIdx.y * MBn + blockIdx.x;
  const int swz = (bid & 7) * (nwg >> 3) + (bid >> 3);
  const int m0 = (swz % MBn) * 128, n0 = (swz / MBn) * 128;
  const int klen = K / (int)gridDim.z;
  const int kb0 = blockIdx.z * klen;
  const int row = l & 15;
  const int kc8 = ((l >> 4) ^ ((l >> 1) & 3)) * 8;   // swizzled read chunk
  const int gsc = ((l & 3) ^ ((l >> 3) & 3)) * 8;    // swizzled global source chunk
  const int sr = l >> 2;
  f32x4 acc[4][4];
#pragma unroll
  for (int a = 0; a < 4; ++a)
#pragma unroll
    for (int b = 0; b < 4; ++b) acc[a][b] = zero4();

  auto STAGE = [&](int buf, int k0) {
    u16* base = sm + buf * NB * 4096;
#pragma unroll
    for (int s2 = 0; s2 < 2; ++s2) {
      int seg = w*2 + s2;                    // 0..7, 16 rows each
      int r = seg*16 + sr;
      size_t ga = (size_t)(m0 + r)*K + k0 + gsc;
      size_t gb = (size_t)(n0 + r)*K + k0 + gsc;
      GLDS16(&Ah[ga], base + seg*512);
      GLDS16(&Bh[gb], base + 4096 + seg*512);
      if (SPLIT) {
        GLDS16(&Al[ga], base + 2*4096 + seg*512);
        GLDS16(&Bl[gb], base + 3*4096 + seg*512);
      }
    }
  };

  const int nt = klen >> 5;
  STAGE(0, kb0);
  __syncthreads();                            // buf0 ready
  int cur = 0;
  for (int kt = 0; kt < nt; ++kt) {
    if (kt + 1 < nt) STAGE(cur ^ 1, kb0 + (kt + 1) * 32);
    u16* bA  = sm + cur * NB * 4096;
    u16* bB  = bA + 4096;
    u16* bAl = bA + 2*4096;
    u16* bBl = bA + 3*4096;
    bhalf8 af[4], afl[4];
#pragma unroll
    for (int mf = 0; mf < 4; ++mf) {
      af[mf] = LD8(&bA[(wm*64 + mf*16 + row)*32 + kc8]);
      if (SPLIT) afl[mf] = LD8(&bAl[(wm*64 + mf*16 + row)*32 + kc8]);
    }
#pragma unroll
    for (int nf = 0; nf < 4; ++nf) {
      bhalf8 bfh = LD8(&bB[(wn*64 + nf*16 + row)*32 + kc8]);
      bhalf8 bfl;
      if (SPLIT) bfl = LD8(&bBl[(wn*64 + nf*16 + row)*32 + kc8]);
#pragma unroll
      for (int mf = 0; mf < 4; ++mf) {
        acc[mf][nf] = MFMA(af[mf], bfh, acc[mf][nf]);
        if (SPLIT) {
          acc[mf][nf] = MFMA(af[mf], bfl, acc[mf][nf]);
          acc[mf][nf] = MFMA(afl[mf], bfh, acc[mf][nf]);
        }
      }
    }
    __syncthreads();
    cur ^= 1;
  }
  if constexpr (EPI == 0) {
    if (n0 < 512) {
      // q columns: fused GPT-NeoX rotary. cols c (dd<32) pair with c+32 = acc[mf][nf+2].
#pragma unroll
      for (int mf = 0; mf < 4; ++mf)
#pragma unroll
        for (int i = 0; i < 4; ++i) {
          int r = m0 + wm*64 + mf*16 + (l >> 4)*4 + i;
          int s = r & 4095, b = r >> 12;
#pragma unroll
          for (int nf = 0; nf < 2; ++nf) {
            int c = n0 + wn*64 + nf*16 + (l & 15);
            int hq = c >> 6, dd = c & 31;
            float t1 = acc[mf][nf][i], t2 = acc[mf][nf+2][i];
            float cs = p_cos[s*32 + dd], sn = p_sin[s*32 + dd];
            float o1 = t1*cs - t2*sn, o2 = t2*cs + t1*sn;
            size_t ob = (((size_t)(b*8 + hq))*4096 + s)*64;
            u16 h1 = f2bf(o1); out_hi[ob+dd] = h1;    out_lo[ob+dd] = f2bf(o1 - bf2f(h1));
            u16 h2 = f2bf(o2); out_hi[ob+dd+32] = h2; out_lo[ob+dd+32] = f2bf(o2 - bf2f(h2));
          }
        }
    } else {
#pragma unroll
      for (int mf = 0; mf < 4; ++mf)
#pragma unroll
        for (int nf = 0; nf < 4; ++nf)
#pragma unroll
          for (int i = 0; i < 4; ++i) {
            int r = m0 + wm*64 + mf*16 + (l >> 4)*4 + i;
            int c = n0 + wn*64 + nf*16 + (l & 15);
            float v = acc[mf][nf][i];
            if (n0 == 512) ok[(size_t)r*128 + (c - 512)] = v;
            else if (n0 == 640) ov[(size_t)r*128 + (c - 640)] = v;
            else if (c < 792) og[(size_t)r*24 + (c - 768)] = 1.0f / (1.0f + expf(-v));
          }
    }
  } else if constexpr (EPI == 2) {
#pragma unroll
    for (int mf = 0; mf < 4; ++mf)
#pragma unroll
      for (int nf = 0; nf < 4; ++nf)
#pragma unroll
        for (int i = 0; i < 4; ++i) {
          int r = m0 + wm*64 + mf*16 + (l >> 4)*4 + i;
          int c = n0 + wn*64 + nf*16 + (l & 15);
          p_sin[(size_t)r*N + c] = acc[mf][nf][i];
        }
  } else {  // EPI == 3: split-K partials
    const int M = MBn * 128;
#pragma unroll
    for (int mf = 0; mf < 4; ++mf)
#pragma unroll
      for (int nf = 0; nf < 4; ++nf)
#pragma unroll
        for (int i = 0; i < 4; ++i) {
          int r = m0 + wm*64 + mf*16 + (l >> 4)*4 + i;
          int c = n0 + wn*64 + nf*16 + (l & 15);
          p_sin[((size_t)blockIdx.z * M + r) * (size_t)N + c] = acc[mf][nf][i];
        }
  }
}

// M=1024, N=64, K=4096 split-K GEMM -> per-chunk partials (deterministic, no atomics)
template<bool SPLIT>
__global__ __launch_bounds__(256) void nsa_gemm64(const u16* __restrict__ Ah, const u16* __restrict__ Al,
    const u16* __restrict__ Bh, const u16* __restrict__ Bl, float* __restrict__ part) {
  constexpr int NB = SPLIT ? 4 : 2;
  __shared__ u16 sm[NB * 2 * 2048];          // 2 buffers, tile = 64x32 u16 = 2048
  const int t = threadIdx.x, w = t >> 6, l = t & 63;
  const int mt = blockIdx.x, kc = blockIdx.y;
  const int row = l & 15;
  const int kc8 = ((l >> 4) ^ ((l >> 1) & 3)) * 8;
  const int gsc = ((l & 3) ^ ((l >> 3) & 3)) * 8;
  const int sr = l >> 2;
  f32x4 acc[4];
#pragma unroll
  for (int a = 0; a < 4; ++a) acc[a] = zero4();

  auto STAGE = [&](int buf, int k0) {
    u16* base = sm + buf * NB * 2048;
    int r = w*16 + sr;
    size_t ga = (size_t)(mt*64 + r)*4096 + k0 + gsc;
    size_t gb = (size_t)r*4096 + k0 + gsc;
    GLDS16(&Ah[ga], base + w*512);
    GLDS16(&Bh[gb], base + 2048 + w*512);
    if (SPLIT) {
      GLDS16(&Al[ga], base + 2*2048 + w*512);
      GLDS16(&Bl[gb], base + 3*2048 + w*512);
    }
  };

  STAGE(0, kc*512);
  __syncthreads();
  int cur = 0;
  for (int kt = 0; kt < 16; ++kt) {
    if (kt + 1 < 16) STAGE(cur ^ 1, kc*512 + (kt + 1) * 32);
    u16* bA  = sm + cur * NB * 2048;
    u16* bB  = bA + 2048;
    u16* bAl = bA + 2*2048;
    u16* bBl = bA + 3*2048;
    bhalf8 a = LD8(&bA[(w*16 + row)*32 + kc8]);
    bhalf8 al;
    if (SPLIT) al = LD8(&bAl[(w*16 + row)*32 + kc8]);
#pragma unroll
    for (int nf = 0; nf < 4; ++nf) {
      bhalf8 b = LD8(&bB[(nf*16 + row)*32 + kc8]);
      bhalf8 bl;
      if (SPLIT) bl = LD8(&bBl[(nf*16 + row)*32 + kc8]);
      acc[nf] = MFMA(a, b, acc[nf]);
      if (SPLIT) {
        acc[nf] = MFMA(a, bl, acc[nf]);
        acc[nf] = MFMA(al, b, acc[nf]);
      }
    }
    __syncthreads();
    cur ^= 1;
  }
#pragma unroll
  for (int nf = 0; nf < 4; ++nf)
#pragma unroll
    for (int i = 0; i < 4; ++i) {
      int m = mt*64 + w*16 + (l >> 4)*4 + i;
      int d = nf*16 + (l & 15);
      part[((size_t)kc*1024 + m)*64 + d] = acc[nf][i];
    }
}

// ================= attention =================

// compressed: per (b,kh,qblk): 4 GQA heads share one K/V stage. 64 q x 65 keys (pad 80),
// split QK^T; writes gated cout + g-summed imp.
__global__ __launch_bounds__(256) void nsa_attn_comp(const u16* __restrict__ qrh, const u16* __restrict__ qrl,
    const u16* __restrict__ ckh, const u16* __restrict__ ckl, const u16* __restrict__ cvT,
    const float* __restrict__ g32, float* __restrict__ comb, float* __restrict__ imp) {
  __shared__ u16 smem[27392];
  __shared__ float sImp[4 * 80];
  u16* sKh = smem;            // 80*72 = 5760
  u16* sKl = smem + 5760;     // 5760
  u16* sVT = smem + 11520;    // 64*104 = 6656
  u16* sQh = smem + 18176;    // 64*72 = 4608
  u16* sQl = smem + 22784;    // 64*72 = 4608
  u16* sP  = smem + 18176;    // alias over sQ (64*104 = 6656 <= 9216)
  const int t = threadIdx.x, w = t >> 6, l = t & 63;
  const int bid = blockIdx.x;  // 1024
  const int qt = bid & 63, kh = (bid >> 6) & 1, b = bid >> 7;
  const int row = l & 15, kg = (l >> 4) * 8;
  size_t kbase = (size_t)(b*2 + kh) * 80 * 64;
  size_t vbase = (size_t)(b*2 + kh) * 64 * 96;
  for (int e = t; e < 640; e += 256) {
    int r = e >> 3, c = (e & 7) * 8;
    *(int4*)&sKh[r*72 + c] = *(const int4*)&ckh[kbase + r*64 + c];
    *(int4*)&sKl[r*72 + c] = *(const int4*)&ckl[kbase + r*64 + c];
  }
  for (int e = t; e < 768; e += 256) {
    int r = e / 12, ch = e % 12;
    *(int4*)&sVT[r*104 + ch*8] = *(const int4*)&cvT[vbase + (size_t)r*96 + ch*8];
  }
  float accImp = 0.f;
  for (int g = 0; g < 4; ++g) {
    if (g) __syncthreads();   // prev PV reads of sP done before Q reload
    size_t qbase = ((size_t)((b*2 + kh)*4 + g)*4096 + qt*64) * 64;
    for (int e = t; e < 512; e += 256) {
      int r = e >> 3, c = (e & 7) * 8;
      *(int4*)&sQh[r*72 + c] = *(const int4*)&qrh[qbase + r*64 + c];
      *(int4*)&sQl[r*72 + c] = *(const int4*)&qrl[qbase + r*64 + c];
    }
    __syncthreads();          // Q (and on g=0, K/V) ready
    f32x4 sc[5];
#pragma unroll
    for (int nf = 0; nf < 5; ++nf) sc[nf] = zero4();
#pragma unroll
    for (int kk = 0; kk < 2; ++kk) {
      bhalf8 ah = LD8(&sQh[(w*16 + row)*72 + kk*32 + kg]);
      bhalf8 al = LD8(&sQl[(w*16 + row)*72 + kk*32 + kg]);
#pragma unroll
      for (int nf = 0; nf < 5; ++nf) {
        bhalf8 bh = LD8(&sKh[(nf*16 + row)*72 + kk*32 + kg]);
        bhalf8 bl = LD8(&sKl[(nf*16 + row)*72 + kk*32 + kg]);
        sc[nf] = MFMA(ah, bh, sc[nf]);
        sc[nf] = MFMA(ah, bl, sc[nf]);
        sc[nf] = MFMA(al, bh, sc[nf]);
      }
    }
    float mx[4] = {-1e30f, -1e30f, -1e30f, -1e30f};
#pragma unroll
    for (int nf = 0; nf < 5; ++nf)
#pragma unroll
      for (int i = 0; i < 4; ++i) {
        int col = nf*16 + (l & 15);
        float v = (col < 65) ? sc[nf][i] * 0.125f : -1e30f;
        sc[nf][i] = v;
        mx[i] = fmaxf(mx[i], v);
      }
#pragma unroll
    for (int i = 0; i < 4; ++i)
#pragma unroll
      for (int o = 1; o < 16; o <<= 1) mx[i] = fmaxf(mx[i], __shfl_xor(mx[i], o));
    float sum[4] = {0.f, 0.f, 0.f, 0.f};
#pragma unroll
    for (int nf = 0; nf < 5; ++nf)
#pragma unroll
      for (int i = 0; i < 4; ++i) {
        int col = nf*16 + (l & 15);
        float p = (col < 65) ? expf(sc[nf][i] - mx[i]) : 0.f;
        sc[nf][i] = p;
        sum[i] += p;
      }
#pragma unroll
    for (int i = 0; i < 4; ++i)
#pragma unroll
      for (int o = 1; o < 16; o <<= 1) sum[i] += __shfl_xor(sum[i], o);
    float inv[4];
#pragma unroll
    for (int i = 0; i < 4; ++i) inv[i] = 1.0f / sum[i];
    __syncthreads();          // all QK reads of sQ done; sP may alias it now
#pragma unroll
    for (int nf = 0; nf < 5; ++nf)
#pragma unroll
      for (int i = 0; i < 4; ++i)
        sP[(w*16 + (l >> 4)*4 + i)*104 + nf*16 + (l & 15)] = f2bf(sc[nf][i] * inv[i]);
#pragma unroll
    for (int i = 0; i < 4; ++i)
      sP[(w*16 + (l >> 4)*4 + i)*104 + 80 + (l & 15)] = 0;  // zero pad cols 80..95
#pragma unroll
    for (int nf = 0; nf < 5; ++nf) {
      float cs = 0.f;
#pragma unroll
      for (int i = 0; i < 4; ++i) cs += sc[nf][i] * inv[i];
      cs += __shfl_xor(cs, 16);
      cs += __shfl_xor(cs, 32);
      if (l < 16) sImp[w*80 + nf*16 + l] = cs;
    }
    __syncthreads();          // sP + sImp visible
    if (t < 64) {
      int n = t + 1;
      accImp += sImp[n] + sImp[80 + n] + sImp[160 + n] + sImp[240 + n];
    }
    f32x4 ov[4];
#pragma unroll
    for (int nf = 0; nf < 4; ++nf) ov[nf] = zero4();
#pragma unroll
    for (int kk = 0; kk < 3; ++kk) {
      bhalf8 a = LD8(&sP[(w*16 + row)*104 + kk*32 + kg]);
#pragma unroll
      for (int nf = 0; nf < 4; ++nf) {
        bhalf8 bv = LD8(&sVT[(nf*16 + row)*104 + kk*32 + kg]);
        ov[nf] = MFMA(a, bv, ov[nf]);
      }
    }
    int hq = kh*4 + g;
#pragma unroll
    for (int i = 0; i < 4; ++i) {
      int q = qt*64 + w*16 + (l >> 4)*4 + i;
      float gate = g32[((size_t)b*4096 + q)*24 + hq*3 + 0];
#pragma unroll
      for (int nf = 0; nf < 4; ++nf) {
        int d = nf*16 + (l & 15);
        comb[(((size_t)b*4096 + q)*8 + hq)*64 + d] = gate * ov[nf][i];
      }
    }
  }
  if (t < 64) imp[(size_t)bid*64 + t] = accImp * (1.0f/256.0f);
}

__global__ __launch_bounds__(64) void nsa_top2(const float* __restrict__ imp, int* __restrict__ sel) {
  int blk = blockIdx.x;  // (b*2+kh)*64 + qt
  int l = threadIdx.x;
  float v = imp[(size_t)blk*64 + l];
  float v1 = v; int i1 = l;
#pragma unroll
  for (int o = 1; o < 64; o <<= 1) {
    float ovv = __shfl_xor(v1, o); int oi = __shfl_xor(i1, o);
    if (ovv > v1 || (ovv == v1 && oi < i1)) { v1 = ovv; i1 = oi; }
  }
  float v2 = (l == i1) ? -3.0e38f : v; int i2 = l;
#pragma unroll
  for (int o = 1; o < 64; o <<= 1) {
    float ovv = __shfl_xor(v2, o); int oi = __shfl_xor(i2, o);
    if (ovv > v2 || (ovv == v2 && oi < i2)) { v2 = ovv; i2 = oi; }
  }
  if (l == 0) { sel[blk*2 + 0] = i1; sel[blk*2 + 1] = i2; }
}

// fine: per (b,kh,qblk): 4 g-heads of 64 q x 192 keys ([sel0, sel1, own])
__global__ __launch_bounds__(256) void nsa_attn_fine(const u16* __restrict__ qrh, const u16* __restrict__ kr,
    const u16* __restrict__ vT, const int* __restrict__ sel, const float* __restrict__ g32,
    float* __restrict__ comb) {
  __shared__ u16 smem[31232];
  u16* sK  = smem;            // 192*72 = 13824 (aliased by sP 64*200 after QK)
  u16* sP  = smem;
  u16* sVT = smem + 13824;    // 64*200
  u16* sQ  = smem + 26624;    // 64*72
  const int t = threadIdx.x, w = t >> 6, l = t & 63;
  const int bid = blockIdx.x;
  const int qt = bid & 63, kh = (bid >> 6) & 1, b = bid >> 7;
  const int row = l & 15, kg = (l >> 4) * 8;
  const int s0 = sel[bid*2 + 0] & 63, s1 = sel[bid*2 + 1] & 63;
  size_t kvb = (size_t)(b*2 + kh) * 4096 * 64;
  size_t vtb = (size_t)(b*2 + kh) * 64 * 4096;
  for (int e = t; e < 1536; e += 256) {  // VT: 64 rows x 24 chunks
    int r = e / 24, ch = e % 24;
    int n0 = ch * 8, bi = n0 >> 6;
    int blkid = (bi == 0) ? s0 : ((bi == 1) ? s1 : qt);
    int sidx = blkid*64 + (n0 & 63);
    *(int4*)&sVT[r*200 + n0] = *(const int4*)&vT[vtb + (size_t)r*4096 + sidx];
  }
  for (int g = 0; g < 4; ++g) {
    __syncthreads();
    for (int e = t; e < 1536; e += 256) {  // K: 192 rows x 8 chunks
      int r = e >> 3, c = (e & 7) * 8;
      int bi = r >> 6;
      int blkid = (bi == 0) ? s0 : ((bi == 1) ? s1 : qt);
      int sidx = blkid*64 + (r & 63);
      *(int4*)&sK[r*72 + c] = *(const int4*)&kr[kvb + (size_t)sidx*64 + c];
    }
    size_t qbase = ((size_t)((b*2 + kh)*4 + g)*4096 + qt*64) * 64;
    for (int e = t; e < 512; e += 256) {
      int r = e >> 3, c = (e & 7) * 8;
      *(int4*)&sQ[r*72 + c] = *(const int4*)&qrh[qbase + r*64 + c];
    }
    __syncthreads();
    f32x4 sc[12];
#pragma unroll
    for (int nf = 0; nf < 12; ++nf) sc[nf] = zero4();
#pragma unroll
    for (int kk = 0; kk < 2; ++kk) {
      bhalf8 a = LD8(&sQ[(w*16 + row)*72 + kk*32 + kg]);
#pragma unroll
      for (int nf = 0; nf < 12; ++nf) {
        bhalf8 bk = LD8(&sK[(nf*16 + row)*72 + kk*32 + kg]);
        sc[nf] = MFMA(a, bk, sc[nf]);
      }
    }
    float mx[4] = {-1e30f, -1e30f, -1e30f, -1e30f};
#pragma unroll
    for (int nf = 0; nf < 12; ++nf)
#pragma unroll
      for (int i = 0; i < 4; ++i) {
        float v = sc[nf][i] * 0.125f;
        sc[nf][i] = v;
        mx[i] = fmaxf(mx[i], v);
      }
#pragma unroll
    for (int i = 0; i < 4; ++i)
#pragma unroll
      for (int o = 1; o < 16; o <<= 1) mx[i] = fmaxf(mx[i], __shfl_xor(mx[i], o));
    float sum[4] = {0.f, 0.f, 0.f, 0.f};
#pragma unroll
    for (int nf = 0; nf < 12; ++nf)
#pragma unroll
      for (int i = 0; i < 4; ++i) {
        float p = expf(sc[nf][i] - mx[i]);
        sc[nf][i] = p;
        sum[i] += p;
      }
#pragma unroll
    for (int i = 0; i < 4; ++i)
#pragma unroll
      for (int o = 1; o < 16; o <<= 1) sum[i] += __shfl_xor(sum[i], o);
    float inv[4];
#pragma unroll
    for (int i = 0; i < 4; ++i) inv[i] = 1.0f / sum[i];
    __syncthreads();  // all done reading sK -> sP may alias
#pragma unroll
    for (int nf = 0; nf < 12; ++nf)
#pragma unroll
      for (int i = 0; i < 4; ++i)
        sP[(w*16 + (l >> 4)*4 + i)*200 + nf*16 + (l & 15)] = f2bf(sc[nf][i] * inv[i]);
    __syncthreads();
    f32x4 ovv[4];
#pragma unroll
    for (int nf = 0; nf < 4; ++nf) ovv[nf] = zero4();
#pragma unroll
    for (int kk = 0; kk < 6; ++kk) {
      bhalf8 a = LD8(&sP[(w*16 + row)*200 + kk*32 + kg]);
#pragma unroll
      for (int nf = 0; nf < 4; ++nf) {
        bhalf8 bv = LD8(&sVT[(nf*16 + row)*200 + kk*32 + kg]);
        ovv[nf] = MFMA(a, bv, ovv[nf]);
      }
    }
    int hq = kh*4 + g;
#pragma unroll
    for (int i = 0; i < 4; ++i) {
      int q = qt*64 + w*16 + (l >> 4)*4 + i;
      float gate = g32[((size_t)b*4096 + q)*24 + hq*3 + 1];
#pragma unroll
      for (int nf = 0; nf < 4; ++nf) {
        int d = nf*16 + (l & 15);
        size_t oi = (((size_t)b*4096 + q)*8 + hq)*64 + d;
        comb[oi] += gate * ovv[nf][i];
      }
    }
  }
}

// sliding: per (b,kh,ball): K/V loaded once; 4 q-heads x 2 q-halves iterated
__global__ __launch_bounds__(256) void nsa_attn_slide(const u16* __restrict__ qrh, const u16* __restrict__ kr,
    const u16* __restrict__ vT, const float* __restrict__ g32, float* __restrict__ comb) {
  __shared__ u16 smem[31232];
  u16* sK  = smem;            // 128*72 = 9216
  u16* sVT = smem + 9216;     // 64*136 = 8704
  u16* sQ  = smem + 17920;    // 64*72 = 4608
  u16* sP  = smem + 22528;    // 64*136 = 8704
  const int t = threadIdx.x, w = t >> 6, l = t & 63;
  const int bid = blockIdx.x;  // 8*2*32 = 512
  const int ball = bid & 31, kh = (bid >> 5) & 1, b = bid >> 6;
  const int row = l & 15, kg = (l >> 4) * 8;
  const int ks0 = ball * 128;
  size_t kvb = (size_t)(b*2 + kh) * 4096 * 64;
  size_t vtb = (size_t)(b*2 + kh) * 64 * 4096;
  for (int e = t; e < 1024; e += 256) {
    int r = e >> 3, c = (e & 7) * 8;
    *(int4*)&sK[r*72 + c] = *(const int4*)&kr[kvb + (size_t)(ks0 + r)*64 + c];
  }
  for (int e = t; e < 1024; e += 256) {
    int r = e >> 4, ch = e & 15;
    *(int4*)&sVT[r*136 + ch*8] = *(const int4*)&vT[vtb + (size_t)r*4096 + ks0 + ch*8];
  }
  for (int hq = 0; hq < 4; ++hq) {
    int hh = kh*4 + hq;
    for (int qh = 0; qh < 2; ++qh) {
      int qt = ball*2 + qh;
      __syncthreads();  // prev round's QK reads of sQ done (and g=0: K/V staged)
      size_t qbase = ((size_t)(b*8 + hh)*4096 + qt*64) * 64;
      for (int e = t; e < 512; e += 256) {
        int r = e >> 3, c = (e & 7) * 8;
        *(int4*)&sQ[r*72 + c] = *(const int4*)&qrh[qbase + r*64 + c];
      }
      __syncthreads();
      f32x4 sc[8];
#pragma unroll
      for (int nf = 0; nf < 8; ++nf) sc[nf] = zero4();
#pragma unroll
      for (int kk = 0; kk < 2; ++kk) {
        bhalf8 a = LD8(&sQ[(w*16 + row)*72 + kk*32 + kg]);
#pragma unroll
        for (int nf = 0; nf < 8; ++nf) {
          bhalf8 bk = LD8(&sK[(nf*16 + row)*72 + kk*32 + kg]);
          sc[nf] = MFMA(a, bk, sc[nf]);
        }
      }
      float mx[4] = {-1e30f, -1e30f, -1e30f, -1e30f};
#pragma unroll
      for (int nf = 0; nf < 8; ++nf)
#pragma unroll
        for (int i = 0; i < 4; ++i) {
          float v = sc[nf][i] * 0.125f;
          sc[nf][i] = v;
          mx[i] = fmaxf(mx[i], v);
        }
#pragma unroll
      for (int i = 0; i < 4; ++i)
#pragma unroll
        for (int o = 1; o < 16; o <<= 1) mx[i] = fmaxf(mx[i], __shfl_xor(mx[i], o));
      float sum[4] = {0.f, 0.f, 0.f, 0.f};
#pragma unroll
      for (int nf = 0; nf < 8; ++nf)
#pragma unroll
        for (int i = 0; i < 4; ++i) {
          float p = expf(sc[nf][i] - mx[i]);
          sc[nf][i] = p;
          sum[i] += p;
        }
#pragma unroll
      for (int i = 0; i < 4; ++i)
#pragma unroll
        for (int o = 1; o < 16; o <<= 1) sum[i] += __shfl_xor(sum[i], o);
      float inv[4];
#pragma unroll
      for (int i = 0; i < 4; ++i) inv[i] = 1.0f / sum[i];
      // sP: each wave writes then reads only its own 16-row band -> no barrier needed
#pragma unroll
      for (int nf = 0; nf < 8; ++nf)
#pragma unroll
        for (int i = 0; i < 4; ++i)
          sP[(w*16 + (l >> 4)*4 + i)*136 + nf*16 + (l & 15)] = f2bf(sc[nf][i] * inv[i]);
      f32x4 ovv[4];
#pragma unroll
      for (int nf = 0; nf < 4; ++nf) ovv[nf] = zero4();
#pragma unroll
      for (int kk = 0; kk < 4; ++kk) {
        bhalf8 a = LD8(&sP[(w*16 + row)*136 + kk*32 + kg]);
#pragma unroll
        for (int nf = 0; nf < 4; ++nf) {
          bhalf8 bv = LD8(&sVT[(nf*16 + row)*136 + kk*32 + kg]);
          ovv[nf] = MFMA(a, bv, ovv[nf]);
        }
      }
#pragma unroll
      for (int i = 0; i < 4; ++i) {
        int q = qt*64 + w*16 + (l >> 4)*4 + i;
        float gate = g32[((size_t)b*4096 + q)*24 + hh*3 + 2];
#pragma unroll
        for (int nf = 0; nf < 4; ++nf) {
          int d = nf*16 + (l & 15);
          size_t oi = (((size_t)b*4096 + q)*8 + hh)*64 + d;
          comb[oi] += gate * ovv[nf][i];
        }
      }
    }
  }
}

// ================= launch =================

extern "C" void kernel_launch(void* const* d_in, const int* in_sizes, int n_in,
                              void* d_out, int out_size, void* d_ws, size_t ws_size,
                              hipStream_t stream) {
  const float* x     = (const float*)d_in[0];
  const float* pos   = (const float*)d_in[1];
  const float* pe_w  = (const float*)d_in[2];
  const float* pe_b  = (const float*)d_in[3];
  const float* gamma = (const float*)d_in[4];
  const float* wq    = (const float*)d_in[5];
  const float* wk    = (const float*)d_in[6];
  const float* wv    = (const float*)d_in[7];
  const float* k_pos = (const float*)d_in[8];
  const float* v_pos = (const float*)d_in[9];
  const float* k_w1  = (const float*)d_in[10];
  const float* k_b1  = (const float*)d_in[11];
  const float* k_w2  = (const float*)d_in[12];
  const float* k_b2  = (const float*)d_in[13];
  const float* v_w1  = (const float*)d_in[14];
  const float* v_b1  = (const float*)d_in[15];
  const float* v_w2  = (const float*)d_in[16];
  const float* v_b2  = (const float*)d_in[17];
  const float* mem_k = (const float*)d_in[18];
  const float* mem_v = (const float*)d_in[19];
  const float* w_cmb = (const float*)d_in[20];
  const float* w_out = (const float*)d_in[21];
  float* out = (float*)d_out;
  char* ws = (char*)d_ws;

  // ---- region plan (aliased lifetimes), ~235 MiB total ----
  size_t off = 0;
  auto A = [&](size_t b) { size_t o = off; off += (b + 255) & ~(size_t)255; return o; };
  const size_t oR1 = A(67108864);   // h_hi|h_lo -> w1h|w1l -> comb
  const size_t oR2 = A(67108864);   // qrh|qrl -> cbh
  const size_t oR4 = A(16777216);   // k32 -> th|tl
  const size_t oR5 = A(16777216);   // v32
  const size_t oR6 = A(16777216);   // kbh|kbl (k then v)
  const size_t oR7 = A(16777216);   // kr|vT
  const size_t oR8 = A(3145728);    // g32
  const size_t oR9 = A(2097152);    // wch|wcl -> w2h|w2l|w2vh|w2vl
  const size_t o_cos = A(524288),  o_sin = A(524288);
  const size_t o_pm  = A(8192);
  const size_t o_ck32 = A(327680), o_cv32 = A(327680);
  const size_t o_ckh = A(163840),  o_ckl = A(163840);
  const size_t o_cvT = A(196608);
  const size_t o_woh = A(524288),  o_wol = A(524288);
  const size_t o_imp = A(262144);
  const size_t o_sel = A(8192);
  const size_t o_part = A(2097152);
  const size_t o_part1 = A(33554432);  // MLP split-K partials (2 x 1024 x 4096 f32)

  if (ws_size < off) {  // diagnostic: absmax will read ~ws_size in MiB
    nsa_sentinel<<<(out_size + 255)/256, 256, 0, stream>>>(out, out_size, (float)(ws_size >> 20));
    return;
  }

#define WP(T, o) ((T*)(ws + (o)))
  u16*  h_hi = WP(u16, oR1);           u16* h_lo = WP(u16, oR1 + 33554432);
  u16*  w1h  = WP(u16, oR1);           u16* w1l  = WP(u16, oR1 + 33554432);
  float* comb = WP(float, oR1);
  u16*  qrh  = WP(u16, oR2);           u16* qrl  = WP(u16, oR2 + 33554432);
  u16*  cbh  = WP(u16, oR2);
  float* k32 = WP(float, oR4);
  u16*  th   = WP(u16, oR4);           u16* tl   = WP(u16, oR4 + 8388608);
  float* v32 = WP(float, oR5);
  u16*  kbh  = WP(u16, oR6);           u16* kbl  = WP(u16, oR6 + 8388608);
  u16*  krb  = WP(u16, oR7);           u16* vTb  = WP(u16, oR7 + 8388608);
  float* g32 = WP(float, oR8);
  u16*  wch  = WP(u16, oR9);           u16* wcl  = WP(u16, oR9 + 917504);
  u16*  w2h  = WP(u16, oR9);           u16* w2l  = WP(u16, oR9 + 524288);
  u16*  w2vh = WP(u16, oR9 + 1048576); u16* w2vl = WP(u16, oR9 + 1572864);
  float* cosb = WP(float, o_cos);      float* sinb = WP(float, o_sin);
  float* pm  = WP(float, o_pm);
  float* ck32 = WP(float, o_ck32);     float* cv32 = WP(float, o_cv32);
  u16*  ckh  = WP(u16, o_ckh);         u16* ckl  = WP(u16, o_ckl);
  u16*  cvT  = WP(u16, o_cvT);
  u16*  woh  = WP(u16, o_woh);         u16* wol  = WP(u16, o_wol);
  float* imp = WP(float, o_imp);
  int*  selp = WP(int, o_sel);
  float* part = WP(float, o_part);
  float* part1 = WP(float, o_part1);

  nsa_pos_mean<<<512, 64, 0, stream>>>(pos, pm);
  nsa_hnorm<<<32768, 256, 0, stream>>>(x, pos, pm, pe_w, pe_b, gamma, h_hi, h_lo);
  nsa_wcatT<<<1792, 256, 0, stream>>>(wq, wk, wv, w_cmb, wch, wcl);
  nsa_rope_tab<<<512, 256, 0, stream>>>(cosb, sinb);
  // projection + fused rotary-Q epilogue -> qrh/qrl, k32, v32, g32
  nsa_gemm<true, 0><<<dim3(256, 7, 1), 256, 0, stream>>>(h_hi, h_lo, wch, wcl, 512, 896,
      cosb, sinb, qrh, qrl, k32, v32, g32);
  nsa_rope_k<<<8192, 256, 0, stream>>>(k32, cosb, sinb, krb);
  nsa_vT<<<1024, 256, 0, stream>>>(v32, vTb);
  // k compression MLP (split precision: feeds top-k selection), split-K x2 for TLP
  nsa_kb<<<16384, 256, 0, stream>>>(k32, k_pos, kbh, kbl);           // k32 dead after
  nsa_wT<<<dim3(64, 64), 256, 0, stream>>>(k_w1, w1h, w1l, 4096, 4096);  // h dead
  nsa_gemm<true, 3><<<dim3(8, 32, 2), 256, 0, stream>>>(kbh, kbl, w1h, w1l, 4096, 4096,
      nullptr, part1, nullptr, nullptr, nullptr, nullptr, nullptr);
  nsa_mlp_fuse<true><<<4096, 256, 0, stream>>>(part1, k_b1, th, tl); // th/tl overwrite k32
  nsa_wT<<<dim3(64, 1), 256, 0, stream>>>(k_w2, w2h, w2l, 4096, 64); // wc dead
  nsa_init_c<<<320, 256, 0, stream>>>(mem_k, k_b2, ck32);
  nsa_gemm64<true><<<dim3(16, 8), 256, 0, stream>>>(th, tl, w2h, w2l, part);
  nsa_red64<<<256, 256, 0, stream>>>(part, ck32);
  // v compression MLP (plain bf16: values only), split-K x2
  nsa_kb<<<16384, 256, 0, stream>>>(v32, v_pos, kbh, nullptr);       // v32 dead after
  nsa_wT<<<dim3(64, 64), 256, 0, stream>>>(v_w1, w1h, nullptr, 4096, 4096);
  nsa_gemm<false, 3><<<dim3(8, 32, 2), 256, 0, stream>>>(kbh, nullptr, w1h, nullptr, 4096, 4096,
      nullptr, part1, nullptr, nullptr, nullptr, nullptr, nullptr);
  nsa_mlp_fuse<false><<<4096, 256, 0, stream>>>(part1, v_b1, th, nullptr);
  nsa_wT<<<dim3(64, 1), 256, 0, stream>>>(v_w2, w2vh, nullptr, 4096, 64);
  nsa_init_c<<<320, 256, 0, stream>>>(mem_v, v_b2, cv32);
  nsa_gemm64<false><<<dim3(16, 8), 256, 0, stream>>>(th, nullptr, w2vh, nullptr, part);
  nsa_red64<<<256, 256, 0, stream>>>(part, cv32);
  nsa_ckcv<<<704, 256, 0, stream>>>(ck32, cv32, ckh, ckl, cvT);
  // attention branches -> gated combine (comb overwrites w1 region)
  nsa_attn_comp<<<1024, 256, 0, stream>>>(qrh, qrl, ckh, ckl, cvT, g32, comb, imp);
  nsa_top2<<<1024, 64, 0, stream>>>(imp, selp);
  nsa_attn_fine<<<1024, 256, 0, stream>>>(qrh, krb, vTb, selp, g32, comb);
  nsa_attn_slide<<<512, 256, 0, stream>>>(qrh, krb, vTb, g32, comb);
  // output projection (plain bf16; cbh overwrites qr region)
  nsa_comb_bf<<<16384, 256, 0, stream>>>(comb, cbh);
  nsa_wT<<<dim3(8, 8), 256, 0, stream>>>(w_out, woh, nullptr, 512, 512);
  nsa_gemm<false, 2><<<dim3(256, 4, 1), 256, 0, stream>>>(cbh, nullptr, woh, nullptr, 512, 512,
      nullptr, out, nullptr, nullptr, nullptr, nullptr, nullptr);
#undef WP
}

// Round 7
// 697.660 us; speedup vs baseline: 1.2240x; 1.0576x over previous
//
#include <hip/hip_runtime.h>
#include <stdint.h>

#define DEVI static __device__ __forceinline__
typedef unsigned short u16;
typedef __bf16 bhalf8 __attribute__((ext_vector_type(8)));
typedef float f32x4 __attribute__((ext_vector_type(4)));

DEVI u16 f2bf(float f) {
  union { float f; unsigned u; } v; v.f = f;
  unsigned r = v.u + 0x7FFFu + ((v.u >> 16) & 1u);
  return (u16)(r >> 16);
}
DEVI float bf2f(u16 h) {
  union { unsigned u; float f; } v; v.u = ((unsigned)h) << 16;
  return v.f;
}
DEVI f32x4 MFMA(bhalf8 a, bhalf8 b, f32x4 c) {
  return __builtin_amdgcn_mfma_f32_16x16x32_bf16(a, b, c, 0, 0, 0);
}
DEVI bhalf8 LD8(const u16* p) { return *(const bhalf8*)p; }
DEVI f32x4 zero4() { f32x4 z = {0.f, 0.f, 0.f, 0.f}; return z; }

// async global->LDS, 16B per lane, dest = wave-uniform base + lane*16
#define GLDS16(gp, lp) __builtin_amdgcn_global_load_lds( \
    (const __attribute__((address_space(1))) void*)(gp), \
    (__attribute__((address_space(3))) void*)(lp), 16, 0, 0)

// ================= prep / elementwise =================

__global__ __launch_bounds__(64) void nsa_pos_mean(const float* __restrict__ pos, float* __restrict__ pm) {
  int blk = blockIdx.x, l = threadIdx.x;
  const float* p = pos + (size_t)(blk * 64 + l) * 3;
  float a = p[0], b = p[1], c = p[2];
#pragma unroll
  for (int o = 32; o; o >>= 1) { a += __shfl_down(a, o); b += __shfl_down(b, o); c += __shfl_down(c, o); }
  if (l == 0) { pm[blk*3+0] = a * (1.f/64.f); pm[blk*3+1] = b * (1.f/64.f); pm[blk*3+2] = c * (1.f/64.f); }
}

__global__ __launch_bounds__(256) void nsa_hnorm(const float* __restrict__ x, const float* __restrict__ pos,
    const float* __restrict__ pm, const float* __restrict__ pew, const float* __restrict__ peb,
    const float* __restrict__ gamma, u16* __restrict__ hhi, u16* __restrict__ hlo) {
  int n = blockIdx.x, t = threadIdx.x;
  int blk = n >> 6;
  float r0 = pos[(size_t)n*3+0] - pm[blk*3+0];
  float r1 = pos[(size_t)n*3+1] - pm[blk*3+1];
  float r2 = pos[(size_t)n*3+2] - pm[blk*3+2];
  int c0 = t, c1 = t + 256;
  const float* xr = x + (size_t)n * 512;
  float v0 = xr[c0] + r0*pew[c0] + r1*pew[512+c0] + r2*pew[1024+c0] + peb[c0];
  float v1 = xr[c1] + r0*pew[c1] + r1*pew[512+c1] + r2*pew[1024+c1] + peb[c1];
  float ss = v0*v0 + v1*v1;
#pragma unroll
  for (int o = 32; o; o >>= 1) ss += __shfl_down(ss, o);
  __shared__ float red[4];
  if ((t & 63) == 0) red[t >> 6] = ss;
  __syncthreads();
  float rms = 1.0f / sqrtf((red[0]+red[1]+red[2]+red[3]) * (1.0f/512.0f) + 1e-6f);
  float h0 = v0 * rms * gamma[c0], h1 = v1 * rms * gamma[c1];
  u16 a0 = f2bf(h0); hhi[(size_t)n*512+c0] = a0; hlo[(size_t)n*512+c0] = f2bf(h0 - bf2f(a0));
  u16 a1 = f2bf(h1); hhi[(size_t)n*512+c1] = a1; hlo[(size_t)n*512+c1] = f2bf(h1 - bf2f(a1));
}

// WcatT[n][k], n<896: cols of [wq|wk|wv|w_combine|pad]
__global__ __launch_bounds__(256) void nsa_wcatT(const float* __restrict__ wq, const float* __restrict__ wk,
    const float* __restrict__ wv, const float* __restrict__ wc, u16* __restrict__ hi, u16* __restrict__ lo) {
  int idx = blockIdx.x * 256 + threadIdx.x;  // 896*512
  if (idx >= 896*512) return;
  int k = idx & 511, n = idx >> 9;
  float v;
  if (n < 512) v = wq[(size_t)k*512 + n];
  else if (n < 640) v = wk[(size_t)k*128 + n - 512];
  else if (n < 768) v = wv[(size_t)k*128 + n - 640];
  else if (n < 792) v = wc[(size_t)k*24 + n - 768];
  else v = 0.f;
  u16 h = f2bf(v); hi[idx] = h; lo[idx] = f2bf(v - bf2f(h));
}

__global__ __launch_bounds__(256) void nsa_rope_tab(float* __restrict__ ct, float* __restrict__ st) {
  int idx = blockIdx.x * 256 + threadIdx.x;  // 4096*32
  if (idx >= 4096*32) return;
  int s = idx >> 5, i = idx & 31;
  float e = (float)(2*i) * (1.0f/64.0f);
  float inv = 1.0f / powf(10000.0f, e);
  float f = (float)s * inv;
  ct[idx] = cosf(f); st[idx] = sinf(f);
}

// v16 (B,KH,S,64 bf16) -> vT (B,KH,64,S bf16)
__global__ __launch_bounds__(256) void nsa_vT16(const u16* __restrict__ v16, u16* __restrict__ vT) {
  int blk = blockIdx.x;  // (b*2+kh)*64 + chunk
  int st = (blk & 63) * 64, bkh = blk >> 6;
  __shared__ u16 tile[64][72];
  int t = threadIdx.x;
  int s = t >> 2, c0 = (t & 3) * 16;
  const u16* src = v16 + ((size_t)bkh*4096 + st + s) * 64;
  *(int4*)&tile[s][c0]   = *(const int4*)&src[c0];
  *(int4*)&tile[s][c0+8] = *(const int4*)&src[c0+8];
  __syncthreads();
  int d = t >> 2, s0 = (t & 3) * 16;
  u16* dst = vT + ((size_t)bkh*64 + d)*4096 + st + s0;
#pragma unroll
  for (int j = 0; j < 16; ++j) dst[j] = tile[s0+j][d];
}

// transpose + split-convert: src f32 [K][N] -> dhi/dlo bf16 [N][K]
__global__ __launch_bounds__(256) void nsa_wT(const float* __restrict__ src, u16* __restrict__ dhi,
    u16* __restrict__ dlo, int K, int N) {
  __shared__ float tile[64][65];
  int k0 = blockIdx.x * 64, n0 = blockIdx.y * 64;
  int t = threadIdx.x, r = t >> 2, c0 = (t & 3) * 16;
#pragma unroll
  for (int j = 0; j < 16; ++j) tile[r][c0+j] = src[(size_t)(k0+r)*N + n0 + c0 + j];
  __syncthreads();
  size_t ob = (size_t)(n0 + r)*K + k0 + c0;
#pragma unroll
  for (int j = 0; j < 16; ++j) {
    float v = tile[c0+j][r];
    u16 h = f2bf(v); dhi[ob+j] = h;
    if (dlo) dlo[ob+j] = f2bf(v - bf2f(h));
  }
}

// init ck/cv f32 (B,KH,80,64): row0 = mem, rows 1..64 = bias2, rows 65..79 = 0
__global__ __launch_bounds__(256) void nsa_init_c(const float* __restrict__ mem, const float* __restrict__ b2,
    float* __restrict__ c32) {
  int idx = blockIdx.x * 256 + threadIdx.x;  // 8*2*80*64 = 81920
  if (idx >= 81920) return;
  int d = idx & 63, n = (idx >> 6) % 80, kh = (idx / (80*64)) & 1;
  c32[idx] = (n == 0) ? mem[kh*64 + d] : ((n <= 64) ? b2[d] : 0.f);
}

// deterministic reduce of split-K partials into c32 rows 1..64
__global__ __launch_bounds__(256) void nsa_red64(const float* __restrict__ part, float* __restrict__ c32) {
  int idx = blockIdx.x * 256 + threadIdx.x;  // 1024*64 = 65536
  int m = idx >> 6, d = idx & 63;
  float s = 0.f;
#pragma unroll
  for (int kc = 0; kc < 8; ++kc) s += part[((size_t)kc*1024 + m)*64 + d];
  int bkh = m >> 6, n = m & 63;
  c32[(((size_t)bkh)*80 + 1 + n)*64 + d] += s;
}

// MLP split-K fuse: sum 2 partial slices + bias + relu -> bf16 hi (and lo if SPLIT)
template<bool SPLIT>
__global__ __launch_bounds__(256) void nsa_mlp_fuse(const float* __restrict__ part,
    const float* __restrict__ bias, u16* __restrict__ oh, u16* __restrict__ ol) {
  size_t i = ((size_t)blockIdx.x * 256 + threadIdx.x) * 4;  // 1024*4096 elems, grid 4096
  int c = (int)(i & 4095);
  float4 a = *(const float4*)&part[i];
  float4 b = *(const float4*)&part[(size_t)4194304 + i];
  float v0 = fmaxf(a.x + b.x + bias[c+0], 0.f);
  float v1 = fmaxf(a.y + b.y + bias[c+1], 0.f);
  float v2 = fmaxf(a.z + b.z + bias[c+2], 0.f);
  float v3 = fmaxf(a.w + b.w + bias[c+3], 0.f);
  u16 h0 = f2bf(v0), h1 = f2bf(v1), h2 = f2bf(v2), h3 = f2bf(v3);
  ((unsigned long long*)oh)[i >> 2] = (unsigned long long)h0 | ((unsigned long long)h1 << 16) |
                                      ((unsigned long long)h2 << 32) | ((unsigned long long)h3 << 48);
  if (SPLIT) {
    u16 l0 = f2bf(v0 - bf2f(h0)), l1 = f2bf(v1 - bf2f(h1));
    u16 l2 = f2bf(v2 - bf2f(h2)), l3 = f2bf(v3 - bf2f(h3));
    ((unsigned long long*)ol)[i >> 2] = (unsigned long long)l0 | ((unsigned long long)l1 << 16) |
                                        ((unsigned long long)l2 << 32) | ((unsigned long long)l3 << 48);
  }
}

// ck f32 -> ck hi/lo (same layout); cv f32 -> cvT bf16 (B,KH,64,96 padded)
__global__ __launch_bounds__(256) void nsa_ckcv(const float* __restrict__ ck32, const float* __restrict__ cv32,
    u16* __restrict__ ckh, u16* __restrict__ ckl, u16* __restrict__ cvT) {
  int idx = blockIdx.x * 256 + threadIdx.x;
  if (idx < 81920) {
    float v = ck32[idx];
    u16 h = f2bf(v); ckh[idx] = h; ckl[idx] = f2bf(v - bf2f(h));
  } else if (idx < 81920 + 8*2*64*96) {
    int j = idx - 81920;
    int cc = j % 96, d = (j / 96) & 63, bkh = j / (96*64);
    float v = (cc < 80) ? cv32[((size_t)bkh*80 + cc)*64 + d] : 0.f;
    cvT[j] = f2bf(v);
  }
}

__global__ __launch_bounds__(256) void nsa_sentinel(float* __restrict__ o, int n, float val) {
  int i = blockIdx.x * 256 + threadIdx.x;
  if (i < n) o[i] = val;
}

// ================= GEMMs =================
// C = A @ B^T ; A: M x K bf16 (hi/lo), BT: N x K bf16 (hi/lo).
// 2-phase double-buffered LDS, global_load_lds w16, both-sides XOR swizzle,
// XCD-aware block swizzle, optional split-K via blockIdx.z.
// EPI 0 (projection): q-cols fused rotary -> split bf16 qr; k-cols -> fused rotary krb +
//   (k+k_pos) split kbh/kbl; v-cols -> v16 bf16 + (v+v_pos) vbh; gate cols -> sigmoid f32.
//   Grid (256,7): per-XCD groups of 8 m-tiles iterate all 7 n-tiles (A L2-reuse).
// EPI 2: f32 out (p_sin = out).  EPI 3: f32 partials to p_sin[z][M][N].
template<bool SPLIT, int EPI>
__global__ __launch_bounds__(256) void nsa_gemm(const u16* __restrict__ Ah, const u16* __restrict__ Al,
    const u16* __restrict__ Bh, const u16* __restrict__ Bl, int K, int N,
    const float* __restrict__ p_cos, float* __restrict__ p_sin,
    u16* __restrict__ out_hi, u16* __restrict__ out_lo, float* __restrict__ og,
    const float* __restrict__ kpos, const float* __restrict__ vpos,
    u16* __restrict__ krb, u16* __restrict__ kbh, u16* __restrict__ kbl,
    u16* __restrict__ v16o, u16* __restrict__ vbh) {
  constexpr int NB = SPLIT ? 4 : 2;          // tiles per buffer: Ah,Bh[,Al,Bl]
  __shared__ u16 sm[NB * 2 * 4096];          // 2 buffers, tile = 128x32 u16 = 4096
  const int t = threadIdx.x, w = t >> 6, l = t & 63;
  const int wm = w >> 1, wn = w & 1;
  int m0, n0;
  if constexpr (EPI == 0) {
    // grid (256,7): xcd gets 32 contiguous m-tiles; groups of 8 m iterate all 7 n.
    const int bid = blockIdx.y * 256 + blockIdx.x;
    const int xcd = bid & 7, j = bid >> 3;        // j in [0,224)
    const int mg = j / 56, rem = j % 56;
    const int nn = rem >> 3, mi = rem & 7;
    m0 = ((xcd * 4 + mg) * 8 + mi) * 128;
    n0 = nn * 128;
  } else {
    const int MBn = gridDim.x;
    const int nwg = MBn * gridDim.y;
    const int bid = blockIdx.y * MBn + blockIdx.x;
    const int swz = (bid & 7) * (nwg >> 3) + (bid >> 3);
    m0 = (swz % MBn) * 128; n0 = (swz / MBn) * 128;
  }
  const int klen = K / (int)gridDim.z;
  const int kb0 = blockIdx.z * klen;
  const int row = l & 15;
  const int kc8 = ((l >> 4) ^ ((l >> 1) & 3)) * 8;   // swizzled read chunk
  const int gsc = ((l & 3) ^ ((l >> 3) & 3)) * 8;    // swizzled global source chunk
  const int sr = l >> 2;
  f32x4 acc[4][4];
#pragma unroll
  for (int a = 0; a < 4; ++a)
#pragma unroll
    for (int b = 0; b < 4; ++b) acc[a][b] = zero4();

  auto STAGE = [&](int buf, int k0) {
    u16* base = sm + buf * NB * 4096;
#pragma unroll
    for (int s2 = 0; s2 < 2; ++s2) {
      int seg = w*2 + s2;                    // 0..7, 16 rows each
      int r = seg*16 + sr;
      size_t ga = (size_t)(m0 + r)*K + k0 + gsc;
      size_t gb = (size_t)(n0 + r)*K + k0 + gsc;
      GLDS16(&Ah[ga], base + seg*512);
      GLDS16(&Bh[gb], base + 4096 + seg*512);
      if (SPLIT) {
        GLDS16(&Al[ga], base + 2*4096 + seg*512);
        GLDS16(&Bl[gb], base + 3*4096 + seg*512);
      }
    }
  };

  const int nt = klen >> 5;
  STAGE(0, kb0);
  __syncthreads();                            // buf0 ready
  int cur = 0;
  for (int kt = 0; kt < nt; ++kt) {
    if (kt + 1 < nt) STAGE(cur ^ 1, kb0 + (kt + 1) * 32);
    u16* bA  = sm + cur * NB * 4096;
    u16* bB  = bA + 4096;
    u16* bAl = bA + 2*4096;
    u16* bBl = bA + 3*4096;
    bhalf8 af[4], afl[4];
#pragma unroll
    for (int mf = 0; mf < 4; ++mf) {
      af[mf] = LD8(&bA[(wm*64 + mf*16 + row)*32 + kc8]);
      if (SPLIT) afl[mf] = LD8(&bAl[(wm*64 + mf*16 + row)*32 + kc8]);
    }
#pragma unroll
    for (int nf = 0; nf < 4; ++nf) {
      bhalf8 bfh = LD8(&bB[(wn*64 + nf*16 + row)*32 + kc8]);
      bhalf8 bfl;
      if (SPLIT) bfl = LD8(&bBl[(wn*64 + nf*16 + row)*32 + kc8]);
#pragma unroll
      for (int mf = 0; mf < 4; ++mf) {
        acc[mf][nf] = MFMA(af[mf], bfh, acc[mf][nf]);
        if (SPLIT) {
          acc[mf][nf] = MFMA(af[mf], bfl, acc[mf][nf]);
          acc[mf][nf] = MFMA(afl[mf], bfh, acc[mf][nf]);
        }
      }
    }
    __syncthreads();
    cur ^= 1;
  }
  if constexpr (EPI == 0) {
    if (n0 < 512) {
      // q columns: fused GPT-NeoX rotary. cols c (dd<32) pair with c+32 = acc[mf][nf+2].
#pragma unroll
      for (int mf = 0; mf < 4; ++mf)
#pragma unroll
        for (int i = 0; i < 4; ++i) {
          int r = m0 + wm*64 + mf*16 + (l >> 4)*4 + i;
          int s = r & 4095, b = r >> 12;
#pragma unroll
          for (int nf = 0; nf < 2; ++nf) {
            int c = n0 + wn*64 + nf*16 + (l & 15);
            int hq = c >> 6, dd = c & 31;
            float t1 = acc[mf][nf][i], t2 = acc[mf][nf+2][i];
            float cs = p_cos[s*32 + dd], sn = p_sin[s*32 + dd];
            float o1 = t1*cs - t2*sn, o2 = t2*cs + t1*sn;
            size_t ob = (((size_t)(b*8 + hq))*4096 + s)*64;
            u16 h1 = f2bf(o1); out_hi[ob+dd] = h1;    out_lo[ob+dd] = f2bf(o1 - bf2f(h1));
            u16 h2 = f2bf(o2); out_hi[ob+dd+32] = h2; out_lo[ob+dd+32] = f2bf(o2 - bf2f(h2));
          }
        }
    } else if (n0 == 512) {
      // k columns: fused rotary -> krb; (k + k_pos) split -> kbh/kbl
      int kh = wn;
#pragma unroll
      for (int mf = 0; mf < 4; ++mf)
#pragma unroll
        for (int i = 0; i < 4; ++i) {
          int r = m0 + wm*64 + mf*16 + (l >> 4)*4 + i;
          int s = r & 4095, b = r >> 12;
          int n = s >> 6, sl = s & 63;
          size_t krbase = ((size_t)(b*2 + kh)*4096 + s)*64;
          size_t kbbase = ((size_t)(b*128 + kh*64 + n))*4096 + sl*64;
#pragma unroll
          for (int nf = 0; nf < 2; ++nf) {
            int dd = nf*16 + (l & 15);
            float t1 = acc[mf][nf][i], t2 = acc[mf][nf+2][i];
            float cs = p_cos[s*32 + dd], sn = p_sin[s*32 + dd];
            krb[krbase + dd]      = f2bf(t1*cs - t2*sn);
            krb[krbase + dd + 32] = f2bf(t2*cs + t1*sn);
          }
#pragma unroll
          for (int nf = 0; nf < 4; ++nf) {
            int dk = nf*16 + (l & 15);
            float v = acc[mf][nf][i] + kpos[(kh*64 + sl)*64 + dk];
            u16 h = f2bf(v);
            kbh[kbbase + dk] = h;
            kbl[kbbase + dk] = f2bf(v - bf2f(h));
          }
        }
    } else if (n0 == 640) {
      // v columns: v16 bf16 + (v + v_pos) -> vbh (plain)
      int kh = wn;
#pragma unroll
      for (int mf = 0; mf < 4; ++mf)
#pragma unroll
        for (int i = 0; i < 4; ++i) {
          int r = m0 + wm*64 + mf*16 + (l >> 4)*4 + i;
          int s = r & 4095, b = r >> 12;
          int n = s >> 6, sl = s & 63;
          size_t v16base = ((size_t)(b*2 + kh)*4096 + s)*64;
          size_t vbbase = ((size_t)(b*128 + kh*64 + n))*4096 + sl*64;
#pragma unroll
          for (int nf = 0; nf < 4; ++nf) {
            int dv = nf*16 + (l & 15);
            float vv = acc[mf][nf][i];
            v16o[v16base + dv] = f2bf(vv);
            vbh[vbbase + dv] = f2bf(vv + vpos[(kh*64 + sl)*64 + dv]);
          }
        }
    } else {
#pragma unroll
      for (int mf = 0; mf < 4; ++mf)
#pragma unroll
        for (int nf = 0; nf < 4; ++nf)
#pragma unroll
          for (int i = 0; i < 4; ++i) {
            int r = m0 + wm*64 + mf*16 + (l >> 4)*4 + i;
            int c = n0 + wn*64 + nf*16 + (l & 15);
            if (c < 792) og[(size_t)r*24 + (c - 768)] = 1.0f / (1.0f + expf(-acc[mf][nf][i]));
          }
    }
  } else if constexpr (EPI == 2) {
#pragma unroll
    for (int mf = 0; mf < 4; ++mf)
#pragma unroll
      for (int nf = 0; nf < 4; ++nf)
#pragma unroll
        for (int i = 0; i < 4; ++i) {
          int r = m0 + wm*64 + mf*16 + (l >> 4)*4 + i;
          int c = n0 + wn*64 + nf*16 + (l & 15);
          p_sin[(size_t)r*N + c] = acc[mf][nf][i];
        }
  } else {  // EPI == 3: split-K partials
    const int M = (int)gridDim.x * 128;
#pragma unroll
    for (int mf = 0; mf < 4; ++mf)
#pragma unroll
      for (int nf = 0; nf < 4; ++nf)
#pragma unroll
        for (int i = 0; i < 4; ++i) {
          int r = m0 + wm*64 + mf*16 + (l >> 4)*4 + i;
          int c = n0 + wn*64 + nf*16 + (l & 15);
          p_sin[((size_t)blockIdx.z * M + r) * (size_t)N + c] = acc[mf][nf][i];
        }
  }
}

// M=1024, N=64, K=4096 split-K GEMM -> per-chunk partials (deterministic, no atomics)
template<bool SPLIT>
__global__ __launch_bounds__(256) void nsa_gemm64(const u16* __restrict__ Ah, const u16* __restrict__ Al,
    const u16* __restrict__ Bh, const u16* __restrict__ Bl, float* __restrict__ part) {
  constexpr int NB = SPLIT ? 4 : 2;
  __shared__ u16 sm[NB * 2 * 2048];          // 2 buffers, tile = 64x32 u16 = 2048
  const int t = threadIdx.x, w = t >> 6, l = t & 63;
  const int mt = blockIdx.x, kc = blockIdx.y;
  const int row = l & 15;
  const int kc8 = ((l >> 4) ^ ((l >> 1) & 3)) * 8;
  const int gsc = ((l & 3) ^ ((l >> 3) & 3)) * 8;
  const int sr = l >> 2;
  f32x4 acc[4];
#pragma unroll
  for (int a = 0; a < 4; ++a) acc[a] = zero4();

  auto STAGE = [&](int buf, int k0) {
    u16* base = sm + buf * NB * 2048;
    int r = w*16 + sr;
    size_t ga = (size_t)(mt*64 + r)*4096 + k0 + gsc;
    size_t gb = (size_t)r*4096 + k0 + gsc;
    GLDS16(&Ah[ga], base + w*512);
    GLDS16(&Bh[gb], base + 2048 + w*512);
    if (SPLIT) {
      GLDS16(&Al[ga], base + 2*2048 + w*512);
      GLDS16(&Bl[gb], base + 3*2048 + w*512);
    }
  };

  STAGE(0, kc*512);
  __syncthreads();
  int cur = 0;
  for (int kt = 0; kt < 16; ++kt) {
    if (kt + 1 < 16) STAGE(cur ^ 1, kc*512 + (kt + 1) * 32);
    u16* bA  = sm + cur * NB * 2048;
    u16* bB  = bA + 2048;
    u16* bAl = bA + 2*2048;
    u16* bBl = bA + 3*2048;
    bhalf8 a = LD8(&bA[(w*16 + row)*32 + kc8]);
    bhalf8 al;
    if (SPLIT) al = LD8(&bAl[(w*16 + row)*32 + kc8]);
#pragma unroll
    for (int nf = 0; nf < 4; ++nf) {
      bhalf8 b = LD8(&bB[(nf*16 + row)*32 + kc8]);
      bhalf8 bl;
      if (SPLIT) bl = LD8(&bBl[(nf*16 + row)*32 + kc8]);
      acc[nf] = MFMA(a, b, acc[nf]);
      if (SPLIT) {
        acc[nf] = MFMA(a, bl, acc[nf]);
        acc[nf] = MFMA(al, b, acc[nf]);
      }
    }
    __syncthreads();
    cur ^= 1;
  }
#pragma unroll
  for (int nf = 0; nf < 4; ++nf)
#pragma unroll
    for (int i = 0; i < 4; ++i) {
      int m = mt*64 + w*16 + (l >> 4)*4 + i;
      int d = nf*16 + (l & 15);
      part[((size_t)kc*1024 + m)*64 + d] = acc[nf][i];
    }
}

// ================= attention =================

// compressed: per (b,kh,qblk): 4 GQA heads share one K/V stage. 64 q x 65 keys (pad 80),
// split QK^T; writes gated cout + g-summed imp.
__global__ __launch_bounds__(256) void nsa_attn_comp(const u16* __restrict__ qrh, const u16* __restrict__ qrl,
    const u16* __restrict__ ckh, const u16* __restrict__ ckl, const u16* __restrict__ cvT,
    const float* __restrict__ g32, float* __restrict__ comb, float* __restrict__ imp) {
  __shared__ u16 smem[27392];
  __shared__ float sImp[4 * 80];
  u16* sKh = smem;            // 80*72 = 5760
  u16* sKl = smem + 5760;     // 5760
  u16* sVT = smem + 11520;    // 64*104 = 6656
  u16* sQh = smem + 18176;    // 64*72 = 4608
  u16* sQl = smem + 22784;    // 64*72 = 4608
  u16* sP  = smem + 18176;    // alias over sQ (64*104 = 6656 <= 9216)
  const int t = threadIdx.x, w = t >> 6, l = t & 63;
  const int bid = blockIdx.x;  // 1024
  const int qt = bid & 63, kh = (bid >> 6) & 1, b = bid >> 7;
  const int row = l & 15, kg = (l >> 4) * 8;
  size_t kbase = (size_t)(b*2 + kh) * 80 * 64;
  size_t vbase = (size_t)(b*2 + kh) * 64 * 96;
  for (int e = t; e < 640; e += 256) {
    int r = e >> 3, c = (e & 7) * 8;
    *(int4*)&sKh[r*72 + c] = *(const int4*)&ckh[kbase + r*64 + c];
    *(int4*)&sKl[r*72 + c] = *(const int4*)&ckl[kbase + r*64 + c];
  }
  for (int e = t; e < 768; e += 256) {
    int r = e / 12, ch = e % 12;
    *(int4*)&sVT[r*104 + ch*8] = *(const int4*)&cvT[vbase + (size_t)r*96 + ch*8];
  }
  float accImp = 0.f;
  for (int g = 0; g < 4; ++g) {
    if (g) __syncthreads();   // prev PV reads of sP done before Q reload
    size_t qbase = ((size_t)((b*2 + kh)*4 + g)*4096 + qt*64) * 64;
    for (int e = t; e < 512; e += 256) {
      int r = e >> 3, c = (e & 7) * 8;
      *(int4*)&sQh[r*72 + c] = *(const int4*)&qrh[qbase + r*64 + c];
      *(int4*)&sQl[r*72 + c] = *(const int4*)&qrl[qbase + r*64 + c];
    }
    __syncthreads();          // Q (and on g=0, K/V) ready
    f32x4 sc[5];
#pragma unroll
    for (int nf = 0; nf < 5; ++nf) sc[nf] = zero4();
#pragma unroll
    for (int kk = 0; kk < 2; ++kk) {
      bhalf8 ah = LD8(&sQh[(w*16 + row)*72 + kk*32 + kg]);
      bhalf8 al = LD8(&sQl[(w*16 + row)*72 + kk*32 + kg]);
#pragma unroll
      for (int nf = 0; nf < 5; ++nf) {
        bhalf8 bh = LD8(&sKh[(nf*16 + row)*72 + kk*32 + kg]);
        bhalf8 bl = LD8(&sKl[(nf*16 + row)*72 + kk*32 + kg]);
        sc[nf] = MFMA(ah, bh, sc[nf]);
        sc[nf] = MFMA(ah, bl, sc[nf]);
        sc[nf] = MFMA(al, bh, sc[nf]);
      }
    }
    float mx[4] = {-1e30f, -1e30f, -1e30f, -1e30f};
#pragma unroll
    for (int nf = 0; nf < 5; ++nf)
#pragma unroll
      for (int i = 0; i < 4; ++i) {
        int col = nf*16 + (l & 15);
        float v = (col < 65) ? sc[nf][i] * 0.125f : -1e30f;
        sc[nf][i] = v;
        mx[i] = fmaxf(mx[i], v);
      }
#pragma unroll
    for (int i = 0; i < 4; ++i)
#pragma unroll
      for (int o = 1; o < 16; o <<= 1) mx[i] = fmaxf(mx[i], __shfl_xor(mx[i], o));
    float sum[4] = {0.f, 0.f, 0.f, 0.f};
#pragma unroll
    for (int nf = 0; nf < 5; ++nf)
#pragma unroll
      for (int i = 0; i < 4; ++i) {
        int col = nf*16 + (l & 15);
        float p = (col < 65) ? expf(sc[nf][i] - mx[i]) : 0.f;
        sc[nf][i] = p;
        sum[i] += p;
      }
#pragma unroll
    for (int i = 0; i < 4; ++i)
#pragma unroll
      for (int o = 1; o < 16; o <<= 1) sum[i] += __shfl_xor(sum[i], o);
    float inv[4];
#pragma unroll
    for (int i = 0; i < 4; ++i) inv[i] = 1.0f / sum[i];
    __syncthreads();          // all QK reads of sQ done; sP may alias it now
#pragma unroll
    for (int nf = 0; nf < 5; ++nf)
#pragma unroll
      for (int i = 0; i < 4; ++i)
        sP[(w*16 + (l >> 4)*4 + i)*104 + nf*16 + (l & 15)] = f2bf(sc[nf][i] * inv[i]);
#pragma unroll
    for (int i = 0; i < 4; ++i)
      sP[(w*16 + (l >> 4)*4 + i)*104 + 80 + (l & 15)] = 0;  // zero pad cols 80..95
#pragma unroll
    for (int nf = 0; nf < 5; ++nf) {
      float cs = 0.f;
#pragma unroll
      for (int i = 0; i < 4; ++i) cs += sc[nf][i] * inv[i];
      cs += __shfl_xor(cs, 16);
      cs += __shfl_xor(cs, 32);
      if (l < 16) sImp[w*80 + nf*16 + l] = cs;
    }
    __syncthreads();          // sP + sImp visible
    if (t < 64) {
      int n = t + 1;
      accImp += sImp[n] + sImp[80 + n] + sImp[160 + n] + sImp[240 + n];
    }
    f32x4 ov[4];
#pragma unroll
    for (int nf = 0; nf < 4; ++nf) ov[nf] = zero4();
#pragma unroll
    for (int kk = 0; kk < 3; ++kk) {
      bhalf8 a = LD8(&sP[(w*16 + row)*104 + kk*32 + kg]);
#pragma unroll
      for (int nf = 0; nf < 4; ++nf) {
        bhalf8 bv = LD8(&sVT[(nf*16 + row)*104 + kk*32 + kg]);
        ov[nf] = MFMA(a, bv, ov[nf]);
      }
    }
    int hq = kh*4 + g;
#pragma unroll
    for (int i = 0; i < 4; ++i) {
      int q = qt*64 + w*16 + (l >> 4)*4 + i;
      float gate = g32[((size_t)b*4096 + q)*24 + hq*3 + 0];
#pragma unroll
      for (int nf = 0; nf < 4; ++nf) {
        int d = nf*16 + (l & 15);
        comb[(((size_t)b*4096 + q)*8 + hq)*64 + d] = gate * ov[nf][i];
      }
    }
  }
  if (t < 64) imp[(size_t)bid*64 + t] = accImp * (1.0f/256.0f);
}

__global__ __launch_bounds__(64) void nsa_top2(const float* __restrict__ imp, int* __restrict__ sel) {
  int blk = blockIdx.x;  // (b*2+kh)*64 + qt
  int l = threadIdx.x;
  float v = imp[(size_t)blk*64 + l];
  float v1 = v; int i1 = l;
#pragma unroll
  for (int o = 1; o < 64; o <<= 1) {
    float ovv = __shfl_xor(v1, o); int oi = __shfl_xor(i1, o);
    if (ovv > v1 || (ovv == v1 && oi < i1)) { v1 = ovv; i1 = oi; }
  }
  float v2 = (l == i1) ? -3.0e38f : v; int i2 = l;
#pragma unroll
  for (int o = 1; o < 64; o <<= 1) {
    float ovv = __shfl_xor(v2, o); int oi = __shfl_xor(i2, o);
    if (ovv > v2 || (ovv == v2 && oi < i2)) { v2 = ovv; i2 = oi; }
  }
  if (l == 0) { sel[blk*2 + 0] = i1; sel[blk*2 + 1] = i2; }
}

// fine: per (b,kh,qblk): 4 g-heads of 64 q x 192 keys ([sel0, sel1, own])
__global__ __launch_bounds__(256) void nsa_attn_fine(const u16* __restrict__ qrh, const u16* __restrict__ kr,
    const u16* __restrict__ vT, const int* __restrict__ sel, const float* __restrict__ g32,
    float* __restrict__ comb) {
  __shared__ u16 smem[31232];
  u16* sK  = smem;            // 192*72 = 13824 (aliased by sP 64*200 after QK)
  u16* sP  = smem;
  u16* sVT = smem + 13824;    // 64*200
  u16* sQ  = smem + 26624;    // 64*72
  const int t = threadIdx.x, w = t >> 6, l = t & 63;
  const int bid = blockIdx.x;
  const int qt = bid & 63, kh = (bid >> 6) & 1, b = bid >> 7;
  const int row = l & 15, kg = (l >> 4) * 8;
  const int s0 = sel[bid*2 + 0] & 63, s1 = sel[bid*2 + 1] & 63;
  size_t kvb = (size_t)(b*2 + kh) * 4096 * 64;
  size_t vtb = (size_t)(b*2 + kh) * 64 * 4096;
  for (int e = t; e < 1536; e += 256) {  // VT: 64 rows x 24 chunks
    int r = e / 24, ch = e % 24;
    int n0 = ch * 8, bi = n0 >> 6;
    int blkid = (bi == 0) ? s0 : ((bi == 1) ? s1 : qt);
    int sidx = blkid*64 + (n0 & 63);
    *(int4*)&sVT[r*200 + n0] = *(const int4*)&vT[vtb + (size_t)r*4096 + sidx];
  }
  for (int g = 0; g < 4; ++g) {
    __syncthreads();
    for (int e = t; e < 1536; e += 256) {  // K: 192 rows x 8 chunks
      int r = e >> 3, c = (e & 7) * 8;
      int bi = r >> 6;
      int blkid = (bi == 0) ? s0 : ((bi == 1) ? s1 : qt);
      int sidx = blkid*64 + (r & 63);
      *(int4*)&sK[r*72 + c] = *(const int4*)&kr[kvb + (size_t)sidx*64 + c];
    }
    size_t qbase = ((size_t)((b*2 + kh)*4 + g)*4096 + qt*64) * 64;
    for (int e = t; e < 512; e += 256) {
      int r = e >> 3, c = (e & 7) * 8;
      *(int4*)&sQ[r*72 + c] = *(const int4*)&qrh[qbase + r*64 + c];
    }
    __syncthreads();
    f32x4 sc[12];
#pragma unroll
    for (int nf = 0; nf < 12; ++nf) sc[nf] = zero4();
#pragma unroll
    for (int kk = 0; kk < 2; ++kk) {
      bhalf8 a = LD8(&sQ[(w*16 + row)*72 + kk*32 + kg]);
#pragma unroll
      for (int nf = 0; nf < 12; ++nf) {
        bhalf8 bk = LD8(&sK[(nf*16 + row)*72 + kk*32 + kg]);
        sc[nf] = MFMA(a, bk, sc[nf]);
      }
    }
    float mx[4] = {-1e30f, -1e30f, -1e30f, -1e30f};
#pragma unroll
    for (int nf = 0; nf < 12; ++nf)
#pragma unroll
      for (int i = 0; i < 4; ++i) {
        float v = sc[nf][i] * 0.125f;
        sc[nf][i] = v;
        mx[i] = fmaxf(mx[i], v);
      }
#pragma unroll
    for (int i = 0; i < 4; ++i)
#pragma unroll
      for (int o = 1; o < 16; o <<= 1) mx[i] = fmaxf(mx[i], __shfl_xor(mx[i], o));
    float sum[4] = {0.f, 0.f, 0.f, 0.f};
#pragma unroll
    for (int nf = 0; nf < 12; ++nf)
#pragma unroll
      for (int i = 0; i < 4; ++i) {
        float p = expf(sc[nf][i] - mx[i]);
        sc[nf][i] = p;
        sum[i] += p;
      }
#pragma unroll
    for (int i = 0; i < 4; ++i)
#pragma unroll
      for (int o = 1; o < 16; o <<= 1) sum[i] += __shfl_xor(sum[i], o);
    float inv[4];
#pragma unroll
    for (int i = 0; i < 4; ++i) inv[i] = 1.0f / sum[i];
    __syncthreads();  // all done reading sK -> sP may alias
#pragma unroll
    for (int nf = 0; nf < 12; ++nf)
#pragma unroll
      for (int i = 0; i < 4; ++i)
        sP[(w*16 + (l >> 4)*4 + i)*200 + nf*16 + (l & 15)] = f2bf(sc[nf][i] * inv[i]);
    __syncthreads();
    f32x4 ovv[4];
#pragma unroll
    for (int nf = 0; nf < 4; ++nf) ovv[nf] = zero4();
#pragma unroll
    for (int kk = 0; kk < 6; ++kk) {
      bhalf8 a = LD8(&sP[(w*16 + row)*200 + kk*32 + kg]);
#pragma unroll
      for (int nf = 0; nf < 4; ++nf) {
        bhalf8 bv = LD8(&sVT[(nf*16 + row)*200 + kk*32 + kg]);
        ovv[nf] = MFMA(a, bv, ovv[nf]);
      }
    }
    int hq = kh*4 + g;
#pragma unroll
    for (int i = 0; i < 4; ++i) {
      int q = qt*64 + w*16 + (l >> 4)*4 + i;
      float gate = g32[((size_t)b*4096 + q)*24 + hq*3 + 1];
#pragma unroll
      for (int nf = 0; nf < 4; ++nf) {
        int d = nf*16 + (l & 15);
        size_t oi = (((size_t)b*4096 + q)*8 + hq)*64 + d;
        comb[oi] += gate * ovv[nf][i];
      }
    }
  }
}

// sliding: per (b,kh,ball): K/V loaded once; 4 q-heads x 2 q-halves iterated.
// LAST writer of comb -> emits bf16 cbh directly (comb not stored back).
__global__ __launch_bounds__(256) void nsa_attn_slide(const u16* __restrict__ qrh, const u16* __restrict__ kr,
    const u16* __restrict__ vT, const float* __restrict__ g32, const float* __restrict__ comb,
    u16* __restrict__ cbh) {
  __shared__ u16 smem[31232];
  u16* sK  = smem;            // 128*72 = 9216
  u16* sVT = smem + 9216;     // 64*136 = 8704
  u16* sQ  = smem + 17920;    // 64*72 = 4608
  u16* sP  = smem + 22528;    // 64*136 = 8704
  const int t = threadIdx.x, w = t >> 6, l = t & 63;
  const int bid = blockIdx.x;  // 8*2*32 = 512
  const int ball = bid & 31, kh = (bid >> 5) & 1, b = bid >> 6;
  const int row = l & 15, kg = (l >> 4) * 8;
  const int ks0 = ball * 128;
  size_t kvb = (size_t)(b*2 + kh) * 4096 * 64;
  size_t vtb = (size_t)(b*2 + kh) * 64 * 4096;
  for (int e = t; e < 1024; e += 256) {
    int r = e >> 3, c = (e & 7) * 8;
    *(int4*)&sK[r*72 + c] = *(const int4*)&kr[kvb + (size_t)(ks0 + r)*64 + c];
  }
  for (int e = t; e < 1024; e += 256) {
    int r = e >> 4, ch = e & 15;
    *(int4*)&sVT[r*136 + ch*8] = *(const int4*)&vT[vtb + (size_t)r*4096 + ks0 + ch*8];
  }
  for (int hq = 0; hq < 4; ++hq) {
    int hh = kh*4 + hq;
    for (int qh = 0; qh < 2; ++qh) {
      int qt = ball*2 + qh;
      __syncthreads();  // prev round's QK reads of sQ done (and round 0: K/V staged)
      size_t qbase = ((size_t)(b*8 + hh)*4096 + qt*64) * 64;
      for (int e = t; e < 512; e += 256) {
        int r = e >> 3, c = (e & 7) * 8;
        *(int4*)&sQ[r*72 + c] = *(const int4*)&qrh[qbase + r*64 + c];
      }
      __syncthreads();
      f32x4 sc[8];
#pragma unroll
      for (int nf = 0; nf < 8; ++nf) sc[nf] = zero4();
#pragma unroll
      for (int kk = 0; kk < 2; ++kk) {
        bhalf8 a = LD8(&sQ[(w*16 + row)*72 + kk*32 + kg]);
#pragma unroll
        for (int nf = 0; nf < 8; ++nf) {
          bhalf8 bk = LD8(&sK[(nf*16 + row)*72 + kk*32 + kg]);
          sc[nf] = MFMA(a, bk, sc[nf]);
        }
      }
      float mx[4] = {-1e30f, -1e30f, -1e30f, -1e30f};
#pragma unroll
      for (int nf = 0; nf < 8; ++nf)
#pragma unroll
        for (int i = 0; i < 4; ++i) {
          float v = sc[nf][i] * 0.125f;
          sc[nf][i] = v;
          mx[i] = fmaxf(mx[i], v);
        }
#pragma unroll
      for (int i = 0; i < 4; ++i)
#pragma unroll
        for (int o = 1; o < 16; o <<= 1) mx[i] = fmaxf(mx[i], __shfl_xor(mx[i], o));
      float sum[4] = {0.f, 0.f, 0.f, 0.f};
#pragma unroll
      for (int nf = 0; nf < 8; ++nf)
#pragma unroll
        for (int i = 0; i < 4; ++i) {
          float p = expf(sc[nf][i] - mx[i]);
          sc[nf][i] = p;
          sum[i] += p;
        }
#pragma unroll
      for (int i = 0; i < 4; ++i)
#pragma unroll
        for (int o = 1; o < 16; o <<= 1) sum[i] += __shfl_xor(sum[i], o);
      float inv[4];
#pragma unroll
      for (int i = 0; i < 4; ++i) inv[i] = 1.0f / sum[i];
      // sP: each wave writes then reads only its own 16-row band -> no barrier needed
#pragma unroll
      for (int nf = 0; nf < 8; ++nf)
#pragma unroll
        for (int i = 0; i < 4; ++i)
          sP[(w*16 + (l >> 4)*4 + i)*136 + nf*16 + (l & 15)] = f2bf(sc[nf][i] * inv[i]);
      f32x4 ovv[4];
#pragma unroll
      for (int nf = 0; nf < 4; ++nf) ovv[nf] = zero4();
#pragma unroll
      for (int kk = 0; kk < 4; ++kk) {
        bhalf8 a = LD8(&sP[(w*16 + row)*136 + kk*32 + kg]);
#pragma unroll
        for (int nf = 0; nf < 4; ++nf) {
          bhalf8 bv = LD8(&sVT[(nf*16 + row)*136 + kk*32 + kg]);
          ovv[nf] = MFMA(a, bv, ovv[nf]);
        }
      }
#pragma unroll
      for (int i = 0; i < 4; ++i) {
        int q = qt*64 + w*16 + (l >> 4)*4 + i;
        float gate = g32[((size_t)b*4096 + q)*24 + hh*3 + 2];
#pragma unroll
        for (int nf = 0; nf < 4; ++nf) {
          int d = nf*16 + (l & 15);
          size_t oi = (((size_t)b*4096 + q)*8 + hh)*64 + d;
          cbh[oi] = f2bf(comb[oi] + gate * ovv[nf][i]);
        }
      }
    }
  }
}

// ================= launch =================

extern "C" void kernel_launch(void* const* d_in, const int* in_sizes, int n_in,
                              void* d_out, int out_size, void* d_ws, size_t ws_size,
                              hipStream_t stream) {
  const float* x     = (const float*)d_in[0];
  const float* pos   = (const float*)d_in[1];
  const float* pe_w  = (const float*)d_in[2];
  const float* pe_b  = (const float*)d_in[3];
  const float* gamma = (const float*)d_in[4];
  const float* wq    = (const float*)d_in[5];
  const float* wk    = (const float*)d_in[6];
  const float* wv    = (const float*)d_in[7];
  const float* k_pos = (const float*)d_in[8];
  const float* v_pos = (const float*)d_in[9];
  const float* k_w1  = (const float*)d_in[10];
  const float* k_b1  = (const float*)d_in[11];
  const float* k_w2  = (const float*)d_in[12];
  const float* k_b2  = (const float*)d_in[13];
  const float* v_w1  = (const float*)d_in[14];
  const float* v_b1  = (const float*)d_in[15];
  const float* v_w2  = (const float*)d_in[16];
  const float* v_b2  = (const float*)d_in[17];
  const float* mem_k = (const float*)d_in[18];
  const float* mem_v = (const float*)d_in[19];
  const float* w_cmb = (const float*)d_in[20];
  const float* w_out = (const float*)d_in[21];
  float* out = (float*)d_out;
  char* ws = (char*)d_ws;

  // ---- region plan (aliased lifetimes) ----
  size_t off = 0;
  auto A = [&](size_t b) { size_t o = off; off += (b + 255) & ~(size_t)255; return o; };
  const size_t oR1 = A(67108864);   // h_hi|h_lo -> w1h|w1l -> comb
  const size_t oR2 = A(67108864);   // qrh|qrl (live through slide)
  const size_t oR4 = A(16777216);   // th|tl
  const size_t oR5 = A(16777216);   // v16 | vbh
  const size_t oR6 = A(16777216);   // kbh|kbl
  const size_t oR7 = A(16777216);   // krb|vT
  const size_t oR8 = A(3145728);    // g32
  const size_t oR9 = A(2097152);    // wch|wcl -> w2h|w2l|w2vh|w2vl
  const size_t o_cos = A(524288),  o_sin = A(524288);
  const size_t o_pm  = A(8192);
  const size_t o_ck32 = A(327680), o_cv32 = A(327680);
  const size_t o_ckh = A(163840),  o_ckl = A(163840);
  const size_t o_cvT = A(196608);
  const size_t o_woh = A(524288),  o_wol = A(524288);
  const size_t o_imp = A(262144);
  const size_t o_sel = A(8192);
  const size_t o_part = A(2097152);
  const size_t o_part1 = A(33554432);  // MLP split-K partials -> cbh (33.5 MB)

  if (ws_size < off) {  // diagnostic: absmax will read ~ws_size in MiB
    nsa_sentinel<<<(out_size + 255)/256, 256, 0, stream>>>(out, out_size, (float)(ws_size >> 20));
    return;
  }

#define WP(T, o) ((T*)(ws + (o)))
  u16*  h_hi = WP(u16, oR1);           u16* h_lo = WP(u16, oR1 + 33554432);
  u16*  w1h  = WP(u16, oR1);           u16* w1l  = WP(u16, oR1 + 33554432);
  float* comb = WP(float, oR1);
  u16*  qrh  = WP(u16, oR2);           u16* qrl  = WP(u16, oR2 + 33554432);
  u16*  th   = WP(u16, oR4);           u16* tl   = WP(u16, oR4 + 8388608);
  u16*  v16b = WP(u16, oR5);           u16* vbh  = WP(u16, oR5 + 8388608);
  u16*  kbh  = WP(u16, oR6);           u16* kbl  = WP(u16, oR6 + 8388608);
  u16*  krb  = WP(u16, oR7);           u16* vTb  = WP(u16, oR7 + 8388608);
  float* g32 = WP(float, oR8);
  u16*  wch  = WP(u16, oR9);           u16* wcl  = WP(u16, oR9 + 917504);
  u16*  w2h  = WP(u16, oR9);           u16* w2l  = WP(u16, oR9 + 524288);
  u16*  w2vh = WP(u16, oR9 + 1048576); u16* w2vl = WP(u16, oR9 + 1572864);
  float* cosb = WP(float, o_cos);      float* sinb = WP(float, o_sin);
  float* pm  = WP(float, o_pm);
  float* ck32 = WP(float, o_ck32);     float* cv32 = WP(float, o_cv32);
  u16*  ckh  = WP(u16, o_ckh);         u16* ckl  = WP(u16, o_ckl);
  u16*  cvT  = WP(u16, o_cvT);
  u16*  woh  = WP(u16, o_woh);         u16* wol  = WP(u16, o_wol);
  float* imp = WP(float, o_imp);
  int*  selp = WP(int, o_sel);
  float* part = WP(float, o_part);
  float* part1 = WP(float, o_part1);
  u16*  cbh  = WP(u16, o_part1);       // alias: part1 dead after MLPs

  nsa_pos_mean<<<512, 64, 0, stream>>>(pos, pm);
  nsa_hnorm<<<32768, 256, 0, stream>>>(x, pos, pm, pe_w, pe_b, gamma, h_hi, h_lo);
  nsa_wcatT<<<1792, 256, 0, stream>>>(wq, wk, wv, w_cmb, wch, wcl);
  nsa_rope_tab<<<512, 256, 0, stream>>>(cosb, sinb);
  // projection + fused epilogues: q-rotary -> qr; k -> krb + kbh/kbl; v -> v16 + vbh; gates
  nsa_gemm<true, 0><<<dim3(256, 7, 1), 256, 0, stream>>>(h_hi, h_lo, wch, wcl, 512, 896,
      cosb, sinb, qrh, qrl, g32, k_pos, v_pos, krb, kbh, kbl, v16b, vbh);
  nsa_vT16<<<1024, 256, 0, stream>>>(v16b, vTb);
  // k compression MLP (split precision: feeds top-k selection), split-K x2
  nsa_wT<<<dim3(64, 64), 256, 0, stream>>>(k_w1, w1h, w1l, 4096, 4096);  // h dead
  nsa_gemm<true, 3><<<dim3(8, 32, 2), 256, 0, stream>>>(kbh, kbl, w1h, w1l, 4096, 4096,
      nullptr, part1, nullptr, nullptr, nullptr, nullptr, nullptr, nullptr, nullptr, nullptr,
      nullptr, nullptr);
  nsa_mlp_fuse<true><<<4096, 256, 0, stream>>>(part1, k_b1, th, tl);
  nsa_wT<<<dim3(64, 1), 256, 0, stream>>>(k_w2, w2h, w2l, 4096, 64);  // wc dead
  nsa_init_c<<<320, 256, 0, stream>>>(mem_k, k_b2, ck32);
  nsa_gemm64<true><<<dim3(16, 8), 256, 0, stream>>>(th, tl, w2h, w2l, part);
  nsa_red64<<<256, 256, 0, stream>>>(part, ck32);
  // v compression MLP (plain bf16: values only), split-K x2
  nsa_wT<<<dim3(64, 64), 256, 0, stream>>>(v_w1, w1h, nullptr, 4096, 4096);
  nsa_gemm<false, 3><<<dim3(8, 32, 2), 256, 0, stream>>>(vbh, nullptr, w1h, nullptr, 4096, 4096,
      nullptr, part1, nullptr, nullptr, nullptr, nullptr, nullptr, nullptr, nullptr, nullptr,
      nullptr, nullptr);
  nsa_mlp_fuse<false><<<4096, 256, 0, stream>>>(part1, v_b1, th, nullptr);
  nsa_wT<<<dim3(64, 1), 256, 0, stream>>>(v_w2, w2vh, nullptr, 4096, 64);
  nsa_init_c<<<320, 256, 0, stream>>>(mem_v, v_b2, cv32);
  nsa_gemm64<false><<<dim3(16, 8), 256, 0, stream>>>(th, nullptr, w2vh, nullptr, part);
  nsa_red64<<<256, 256, 0, stream>>>(part, cv32);
  nsa_ckcv<<<704, 256, 0, stream>>>(ck32, cv32, ckh, ckl, cvT);
  // attention branches -> gated combine; slide emits bf16 cbh (part1 region, dead)
  nsa_attn_comp<<<1024, 256, 0, stream>>>(qrh, qrl, ckh, ckl, cvT, g32, comb, imp);
  nsa_top2<<<1024, 64, 0, stream>>>(imp, selp);
  nsa_attn_fine<<<1024, 256, 0, stream>>>(qrh, krb, vTb, selp, g32, comb);
  nsa_attn_slide<<<512, 256, 0, stream>>>(qrh, krb, vTb, g32, comb, cbh);
  // output projection (plain bf16)
  nsa_wT<<<dim3(8, 8), 256, 0, stream>>>(w_out, woh, nullptr, 512, 512);
  nsa_gemm<false, 2><<<dim3(256, 4, 1), 256, 0, stream>>>(cbh, nullptr, woh, nullptr, 512, 512,
      nullptr, out, nullptr, nullptr, nullptr, nullptr, nullptr, nullptr, nullptr, nullptr,
      nullptr, nullptr);
#undef WP
}